// Round 7
// baseline (500.908 us; speedup 1.0000x reference)
//
#include <hip/hip_runtime.h>
#include <hip/hip_bf16.h>
#include <cmath>

#define BATCH 64
#define SEQ   512
#define EMBED 384
#define HEADS 7
#define HSZ   54
#define FFND  2304
#define NTOK  (BATCH*SEQ)
#define QKVN  1152   // 3*378 padded to 9*128
#define EPS   1e-5f
#define SCALE 0.13608276348795434f  // 54^-0.5

typedef __attribute__((ext_vector_type(8))) short s16x8;
typedef __attribute__((ext_vector_type(4))) float f32x4;

__device__ __forceinline__ ushort f2bf(float f) {
  __hip_bfloat16 h = __float2bfloat16(f);
  return *reinterpret_cast<ushort*>(&h);
}

__device__ __forceinline__ void gload16(const void* g, void* l) {
  __builtin_amdgcn_global_load_lds((const __attribute__((address_space(1))) void*)g,
                                   (__attribute__((address_space(3))) void*)l, 16, 0, 0);
}

// ---------------- LayerNorm -> bf16 out, one wave per row ----------------
__global__ __launch_bounds__(256) void ln_bf16_kernel(const float* __restrict__ x,
    const float* __restrict__ g, const float* __restrict__ b, ushort* __restrict__ out) {
  int wave = threadIdx.x >> 6, lane = threadIdx.x & 63;
  int row = (blockIdx.x << 2) + wave;
  const float* xr = x + (size_t)row * EMBED;
  float v[6]; float s = 0.f;
#pragma unroll
  for (int i = 0; i < 6; ++i) { v[i] = xr[lane + (i << 6)]; s += v[i]; }
#pragma unroll
  for (int off = 32; off; off >>= 1) s += __shfl_xor(s, off);
  float mu = s * (1.f / EMBED);
  float var = 0.f;
#pragma unroll
  for (int i = 0; i < 6; ++i) { float d = v[i] - mu; var += d * d; }
#pragma unroll
  for (int off = 32; off; off >>= 1) var += __shfl_xor(var, off);
  float rstd = rsqrtf(var * (1.f / EMBED) + EPS);
  ushort* orow = out + (size_t)row * EMBED;
#pragma unroll
  for (int i = 0; i < 6; ++i) {
    int c = lane + (i << 6);
    orow[c] = f2bf((v[i] - mu) * rstd * g[c] + b[c]);
  }
}

// ---------------- tiled transpose+convert: out[n][k] = bf16(in[k][n]), zero-padded ----------------
__global__ __launch_bounds__(256) void convT_tiled(const float* __restrict__ in,
    ushort* __restrict__ out, int K, int N, int srcK, int srcN) {
  __shared__ float t[32][33];
  int k0 = blockIdx.x << 5, n0 = blockIdx.y << 5;
  int tx = threadIdx.x & 31, ty = threadIdx.x >> 5;
#pragma unroll
  for (int i = 0; i < 4; ++i) {
    int r = ty + i * 8;
    int k = k0 + r, n = n0 + tx;
    t[r][tx] = (k < srcK && n < srcN) ? in[(size_t)k * srcN + n] : 0.f;
  }
  __syncthreads();
#pragma unroll
  for (int i = 0; i < 4; ++i) {
    int r = ty + i * 8;
    int n = n0 + r, k = k0 + tx;
    if (n < N && k < K) out[(size_t)n * K + k] = f2bf(t[tx][r]);
  }
}

// ---------------- QKV weight pack: wqkvt[n][k], n = type*378 + h*54 + hs ----------------
__global__ __launch_bounds__(256) void conv_qkvw_tiled(const float* __restrict__ wq,
    const float* __restrict__ wk, const float* __restrict__ wv, ushort* __restrict__ wt) {
  __shared__ float t[32][33];
  int k0 = blockIdx.x << 5, hs0 = blockIdx.y << 5;
  int z = blockIdx.z, type = z / 7, h = z - type * 7;
  const float* W = (type == 0) ? wq : (type == 1) ? wk : wv;
  int tx = threadIdx.x & 31, ty = threadIdx.x >> 5;
#pragma unroll
  for (int i = 0; i < 4; ++i) {
    int r = ty + i * 8;
    int k = k0 + r, hs = hs0 + tx;
    t[r][tx] = (hs < HSZ) ? W[((size_t)h * EMBED + k) * HSZ + hs] : 0.f;
  }
  __syncthreads();
#pragma unroll
  for (int i = 0; i < 4; ++i) {
    int r = ty + i * 8;
    int hs = hs0 + r, k = k0 + tx;
    if (hs < HSZ) wt[(size_t)(type * 378 + h * HSZ + hs) * EMBED + k0 + tx] = f2bf(t[tx][r]);
  }
}

// ---------------- misc fills ----------------
__global__ __launch_bounds__(256) void fill_misc(const float* __restrict__ bq,
    const float* __restrict__ bk, const float* __restrict__ bv,
    ushort* __restrict__ wt, float* __restrict__ bqkv) {
  int idx = blockIdx.x * 256 + threadIdx.x;
  if (idx < 18 * EMBED) wt[1134 * EMBED + idx] = 0;
  if (idx < QKVN) {
    float bval = 0.f;
    if (idx < 1134) {
      int type = idx / 378, rem = idx - type * 378;
      int h = rem / HSZ, hs = rem - h * HSZ;
      const float* B = (type == 0) ? bq : (type == 1) ? bk : bv;
      bval = B[h * HSZ + hs];
    }
    bqkv[idx] = bval;
  }
}

__global__ __launch_bounds__(256) void pad_aout_kernel(ushort* __restrict__ aout) {
  int idx = blockIdx.x * 256 + threadIdx.x;
  if (idx >= NTOK * 6) return;
  int row = idx / 6, c = idx - row * 6;
  aout[(size_t)row * EMBED + 378 + c] = 0;
}

// ---------------- MFMA flash attention (unchanged from round 6) ----------------
__global__ __launch_bounds__(256) void attn_mfma_kernel(const ushort* __restrict__ qkv,
    ushort* __restrict__ o) {
  __shared__ ushort Ks[2][4096];
  __shared__ ushort Vt[2][4096];
  int tid = threadIdx.x;
  int id = blockIdx.x;
  int xcd = id & 7;
  int sseq = id >> 3;
  int bh = xcd + 8 * (sseq >> 3);
  int qt = (SEQ / 64 - 1) - (sseq & 7);
  int b = bh / HEADS, h = bh - b * HEADS;
  int qr0 = qt << 6;
  int w = tid >> 6, l = tid & 63;
  int lr = l & 15, lg = l >> 4;
  const ushort* base = qkv + (size_t)b * SEQ * QKVN + h * HSZ;

  for (int e = tid; e < 64 * 5; e += 256) {
    int r = e / 5, c = 54 + 2 * (e - r * 5);
    int col = c ^ ((r & 7) << 3);
    *reinterpret_cast<uint*>(&Ks[0][r * 64 + col]) = 0;
    *reinterpret_cast<uint*>(&Ks[1][r * 64 + col]) = 0;
  }
#pragma unroll
  for (int i = 0; i < 7; ++i) {
    int e = tid + i * 256;
    int r = e / 28, c = e - r * 28;
    if (c < 27)
      *reinterpret_cast<uint*>(&Ks[1][r * 64 + ((2 * c) ^ ((r & 7) << 3))]) =
          *reinterpret_cast<const uint*>(base + (size_t)(qr0 + r) * QKVN + 2 * c);
  }
#pragma unroll
  for (int i = 0; i < 7; ++i) {
    int e = tid + i * 256;
    int k = e / 28, c = e - k * 28;
    if (c < 27)
      *reinterpret_cast<uint*>(&Ks[0][k * 64 + ((2 * c) ^ ((k & 7) << 3))]) =
          *reinterpret_cast<const uint*>(base + 378 + (size_t)k * QKVN + 2 * c);
    int ev = e >> 1, par = e & 1;
    int p = ev / 28, cv = ev - p * 28;
    uint u = (cv < 27) ? *reinterpret_cast<const uint*>(base + 756 + (size_t)(2 * p + par) * QKVN + 2 * cv) : 0u;
    uint uo = __shfl_xor(u, 1);
    if (cv < 27) {
      int k0 = 2 * p;
      int s0 = ((k0 >> 5) << 5) | (((k0 >> 2) & 3) << 3) | (((k0 >> 4) & 1) << 2) | (k0 & 3);
      int d = 2 * cv + par;
      uint wv2 = par ? ((uo >> 16) | (u & 0xffff0000u)) : ((u & 0xffffu) | (uo << 16));
      *reinterpret_cast<uint*>(&Vt[0][d * 64 + (s0 ^ ((d & 7) << 3))]) = wv2;
    }
  }
  __syncthreads();

  int qrow = w * 16 + lr;
  s16x8 qf[2];
  qf[0] = *reinterpret_cast<const s16x8*>(&Ks[1][qrow * 64 + ((8 * lg) ^ ((qrow & 7) << 3))]);
  qf[1] = *reinterpret_cast<const s16x8*>(&Ks[1][qrow * 64 + ((32 + 8 * lg) ^ ((qrow & 7) << 3))]);

  int qglob = qr0 + qrow;
  float mrow = -1e30f, lrow = 0.f;
  f32x4 acc[4];
#pragma unroll
  for (int d = 0; d < 4; ++d) acc[d] = (f32x4){0.f, 0.f, 0.f, 0.f};

  uint kreg[7], vreg[7];
  for (int kt = 0; kt <= qt; ++kt) {
    int cur = kt & 1;
    if (kt < qt) {
#pragma unroll
      for (int i = 0; i < 7; ++i) {
        int e = tid + i * 256;
        int k = e / 28, c = e - k * 28;
        kreg[i] = (c < 27) ? *reinterpret_cast<const uint*>(
            base + 378 + (size_t)((kt + 1) * 64 + k) * QKVN + 2 * c) : 0u;
        int ev = e >> 1, par = e & 1;
        int p = ev / 28, cv = ev - p * 28;
        vreg[i] = (cv < 27) ? *reinterpret_cast<const uint*>(
            base + 756 + (size_t)((kt + 1) * 64 + 2 * p + par) * QKVN + 2 * cv) : 0u;
      }
    }
    f32x4 sacc[4];
    __builtin_amdgcn_s_setprio(1);
#pragma unroll
    for (int kb = 0; kb < 4; ++kb) {
      sacc[kb] = (f32x4){0.f, 0.f, 0.f, 0.f};
#pragma unroll
      for (int h2 = 0; h2 < 2; ++h2) {
        int row = kb * 16 + lr;
        s16x8 kf = *reinterpret_cast<const s16x8*>(
            &Ks[cur][row * 64 + ((32 * h2 + 8 * lg) ^ ((row & 7) << 3))]);
        sacc[kb] = __builtin_amdgcn_mfma_f32_16x16x32_bf16(kf, qf[h2], sacc[kb], 0, 0, 0);
      }
    }
    __builtin_amdgcn_s_setprio(0);
    float sv[4][4];
    float mt = -1e30f;
    bool diag = (kt == qt);
#pragma unroll
    for (int kb = 0; kb < 4; ++kb)
#pragma unroll
      for (int r = 0; r < 4; ++r) {
        float s = sacc[kb][r] * SCALE;
        if (diag && (kt * 64 + kb * 16 + 4 * lg + r) > qglob) s = -1e30f;
        sv[kb][r] = s;
        mt = fmaxf(mt, s);
      }
    mt = fmaxf(mt, __shfl_xor(mt, 16));
    mt = fmaxf(mt, __shfl_xor(mt, 32));
    if (!__all(mt - mrow <= 8.f)) {
      float mnew = fmaxf(mrow, mt);
      float al = __expf(mrow - mnew);
#pragma unroll
      for (int d = 0; d < 4; ++d)
#pragma unroll
        for (int r = 0; r < 4; ++r) acc[d][r] *= al;
      lrow *= al;
      mrow = mnew;
    }
    float lsum = 0.f;
    short p16[4][4];
#pragma unroll
    for (int kb = 0; kb < 4; ++kb)
#pragma unroll
      for (int r = 0; r < 4; ++r) {
        float p = __expf(sv[kb][r] - mrow);
        lsum += p;
        p16[kb][r] = (short)f2bf(p);
      }
    lrow += lsum;
    s16x8 af[2];
#pragma unroll
    for (int m = 0; m < 2; ++m)
#pragma unroll
      for (int j = 0; j < 8; ++j) af[m][j] = p16[2 * m + (j >> 2)][j & 3];
    __builtin_amdgcn_s_setprio(1);
#pragma unroll
    for (int m = 0; m < 2; ++m)
#pragma unroll
      for (int d = 0; d < 4; ++d) {
        int row = d * 16 + lr;
        s16x8 vf = *reinterpret_cast<const s16x8*>(
            &Vt[cur][row * 64 + ((32 * m + 8 * lg) ^ ((row & 7) << 3))]);
        acc[d] = __builtin_amdgcn_mfma_f32_16x16x32_bf16(vf, af[m], acc[d], 0, 0, 0);
      }
    __builtin_amdgcn_s_setprio(0);
    if (kt < qt) {
      __syncthreads();
      int nxt = cur ^ 1;
#pragma unroll
      for (int i = 0; i < 7; ++i) {
        int e = tid + i * 256;
        int k = e / 28, c = e - k * 28;
        if (c < 27)
          *reinterpret_cast<uint*>(&Ks[nxt][k * 64 + ((2 * c) ^ ((k & 7) << 3))]) = kreg[i];
        int ev = e >> 1, par = e & 1;
        int p = ev / 28, cv = ev - p * 28;
        uint u = vreg[i];
        uint uo = __shfl_xor(u, 1);
        if (cv < 27) {
          int k0 = 2 * p;
          int s0 = ((k0 >> 5) << 5) | (((k0 >> 2) & 3) << 3) | (((k0 >> 4) & 1) << 2) | (k0 & 3);
          int d = 2 * cv + par;
          uint wv2 = par ? ((uo >> 16) | (u & 0xffff0000u)) : ((u & 0xffffu) | (uo << 16));
          *reinterpret_cast<uint*>(&Vt[nxt][d * 64 + (s0 ^ ((d & 7) << 3))]) = wv2;
        }
      }
      __syncthreads();
    }
  }

  lrow += __shfl_xor(lrow, 16);
  lrow += __shfl_xor(lrow, 32);
  float linv = 1.f / lrow;
  __syncthreads();
  ushort* Olds = &Ks[0][0];
#pragma unroll
  for (int d = 0; d < 4; ++d)
#pragma unroll
    for (int r = 0; r < 4; ++r)
      Olds[(d * 16 + 4 * lg + r) * 64 + w * 16 + lr] = f2bf(acc[d][r] * linv);
  __syncthreads();
  for (int e = tid; e < 64 * 27; e += 256) {
    int q = e / 27, c = e - q * 27;
    uint lo = Olds[(2 * c) * 64 + q];
    uint hi = Olds[(2 * c + 1) * 64 + q];
    *reinterpret_cast<uint*>(&o[(size_t)(b * SEQ + qr0 + q) * EMBED + h * HSZ + 2 * c]) =
        lo | (hi << 16);
  }
}

// ---------------- bf16 MFMA GEMM (128x128 tile, BK=64, 4 waves) ----------------
// MODE 0: C = bf16(A@B + bias)   MODE 1: C = bf16(fast_gelu(A@B + bias))
// MODE 2: C = f32(A@B + bias + resid)
// bf16 modes use an LDS-bounce epilogue (As/Bs reused) for coalesced dwordx4 stores.
template<int KSTEPS, int LDA, int LDB, int MODE>
__global__ __launch_bounds__(256) void mfma_gemm(
    const char* __restrict__ Ab, const char* __restrict__ Btb,
    const float* __restrict__ bias, const float* __restrict__ resid,
    char* __restrict__ Cb, int ncols) {
  __shared__ ushort sh[16384];   // As = sh[0:8192), Bs = sh[8192:16384)
  int tid = threadIdx.x;
  int wv = tid >> 6, l = tid & 63;
  int wr = wv >> 1, wc = wv & 1;
  int lr = l & 15, lg = l >> 4;
  int tok0 = blockIdx.x << 7;
  int col0 = blockIdx.y << 7;

  const char* aptr[4]; const char* bptr[4];
#pragma unroll
  for (int is = 0; is < 4; ++is) {
    int i = is * 256 + tid;
    int row = i >> 3;
    int boff = (i & 7) << 4;
    int sw = boff ^ ((row & 7) << 4);
    aptr[is] = Ab + (size_t)(tok0 + row) * LDA + sw;
    bptr[is] = Btb + (size_t)(col0 + row) * LDB + sw;
  }

  int offA[2][4], offB[2][4];
#pragma unroll
  for (int m = 0; m < 4; ++m) {
    int rowa = wr * 64 + m * 16 + lr;
    int rowb = wc * 64 + m * 16 + lr;
    int sa = (rowa & 7) << 4, sb = (rowb & 7) << 4;
#pragma unroll
    for (int kk = 0; kk < 2; ++kk) {
      int kb = kk * 64 + lg * 16;
      offA[kk][m] = (rowa * 128 + (kb ^ sa)) >> 1;
      offB[kk][m] = 8192 + ((rowb * 128 + (kb ^ sb)) >> 1);
    }
  }

  f32x4 acc[4][4];
#pragma unroll
  for (int m = 0; m < 4; ++m)
#pragma unroll
    for (int n = 0; n < 4; ++n) acc[m][n] = (f32x4){0.f, 0.f, 0.f, 0.f};

  for (int ks = 0; ks < KSTEPS; ++ks) {
#pragma unroll
    for (int is = 0; is < 4; ++is) {
      gload16(aptr[is] + ks * 128, (char*)sh + is * 4096 + wv * 1024);
      gload16(bptr[is] + ks * 128, (char*)sh + 16384 + is * 4096 + wv * 1024);
    }
    __syncthreads();
#pragma unroll
    for (int kk = 0; kk < 2; ++kk) {
      s16x8 af[4], bfr[4];
#pragma unroll
      for (int m = 0; m < 4; ++m) af[m] = *reinterpret_cast<const s16x8*>(&sh[offA[kk][m]]);
#pragma unroll
      for (int n = 0; n < 4; ++n) bfr[n] = *reinterpret_cast<const s16x8*>(&sh[offB[kk][n]]);
#pragma unroll
      for (int m = 0; m < 4; ++m)
#pragma unroll
        for (int n = 0; n < 4; ++n)
          acc[m][n] = __builtin_amdgcn_mfma_f32_16x16x32_bf16(af[m], bfr[n], acc[m][n], 0, 0, 0);
    }
    __syncthreads();
  }

  float bn[4];
  int colr = col0 + wc * 64 + lr;
#pragma unroll
  for (int n = 0; n < 4; ++n) bn[n] = bias[colr + n * 16];

  if constexpr (MODE == 2) {
    int tokr = tok0 + wr * 64 + lg * 4;
    float* C = (float*)Cb;
#pragma unroll
    for (int m = 0; m < 4; ++m)
#pragma unroll
      for (int r = 0; r < 4; ++r) {
        size_t rowbase = (size_t)(tokr + m * 16 + r) * ncols;
#pragma unroll
        for (int n = 0; n < 4; ++n) {
          size_t idx = rowbase + colr + n * 16;
          C[idx] = acc[m][n][r] + bn[n] + resid[idx];
        }
      }
  } else {
    // LDS-bounce epilogue: sh reused as [128][128] bf16 tile,
    // swizzle: physical col = col ^ (((row>>2)&3)<<4)  (conflict-free both sides)
#pragma unroll
    for (int m = 0; m < 4; ++m)
#pragma unroll
      for (int r = 0; r < 4; ++r) {
        int row = wr * 64 + m * 16 + lg * 4 + r;
        int rmask = ((row >> 2) & 3) << 4;
#pragma unroll
        for (int n = 0; n < 4; ++n) {
          float xg = acc[m][n][r] + bn[n];
          if constexpr (MODE == 1) {
            float u2 = xg * (1.5957691216f + 0.0713548162f * xg * xg);  // 2*sqrt(2/pi)*(x+0.044715x^3)
            xg = xg * __builtin_amdgcn_rcpf(1.f + __expf(-u2));          // x*sigmoid(u2)
          }
          int col = wc * 64 + n * 16 + lr;
          sh[row * 128 + (col ^ rmask)] = f2bf(xg);
        }
      }
    __syncthreads();
    ushort* C = (ushort*)Cb;
    int blk = (l & 7) + 8 * (wv & 1);         // 16B-block index 0..15
    int rbase = (l >> 3) + 64 * (wv >> 1);    // rows 0..63 / 64..127
#pragma unroll
    for (int it = 0; it < 8; ++it) {
      int row = rbase + 8 * it;
      int pblk = blk ^ (((row >> 2) & 3) << 1);
      uint4 vv = *reinterpret_cast<const uint4*>(&sh[row * 128 + pblk * 8]);
      *reinterpret_cast<uint4*>(&C[(size_t)(tok0 + row) * ncols + col0 + blk * 8]) = vv;
    }
  }
}

extern "C" void kernel_launch(void* const* d_in, const int* in_sizes, int n_in,
                              void* d_out, int out_size, void* d_ws, size_t ws_size,
                              hipStream_t stream) {
  const float* x    = (const float*)d_in[0];
  const float* wq   = (const float*)d_in[1];
  const float* bq   = (const float*)d_in[2];
  const float* wk   = (const float*)d_in[3];
  const float* bk   = (const float*)d_in[4];
  const float* wv   = (const float*)d_in[5];
  const float* bv   = (const float*)d_in[6];
  const float* wo   = (const float*)d_in[7];
  const float* bo   = (const float*)d_in[8];
  const float* w1   = (const float*)d_in[9];
  const float* b1   = (const float*)d_in[10];
  const float* w2   = (const float*)d_in[11];
  const float* b2   = (const float*)d_in[12];
  const float* ln1g = (const float*)d_in[13];
  const float* ln1b = (const float*)d_in[14];
  const float* ln2g = (const float*)d_in[15];
  const float* ln2b = (const float*)d_in[16];
  float* out = (float*)d_out;

  char* wsb = (char*)d_ws;
  float*  x1    = (float*)wsb;
  ushort* ffnb  = (ushort*)(wsb + 50331648);
  ushort* hb    = (ushort*)(wsb + 50331648);
  ushort* qkvb  = (ushort*)(wsb + 75497472);
  ushort* aout  = (ushort*)(wsb + 150994944);
  ushort* h2b   = (ushort*)(wsb + 201326592);
  ushort* w1t   = (ushort*)(wsb + 226492416);
  ushort* w2t   = (ushort*)(wsb + 228261888);
  ushort* wqkvt = (ushort*)(wsb + 230031360);
  ushort* wot   = (ushort*)(wsb + 230916096);
  float*  bqkv  = (float*)(wsb + 231211008);

  conv_qkvw_tiled<<<dim3(12, 2, 21), 256, 0, stream>>>(wq, wk, wv, wqkvt);
  fill_misc      <<<27, 256, 0, stream>>>(bq, bk, bv, wqkvt, bqkv);
  convT_tiled    <<<dim3(12, 12), 256, 0, stream>>>(wo, wot, EMBED, EMBED, 378, EMBED);
  convT_tiled    <<<dim3(12, 72), 256, 0, stream>>>(w1, w1t, EMBED, FFND, EMBED, FFND);
  convT_tiled    <<<dim3(72, 12), 256, 0, stream>>>(w2, w2t, FFND, EMBED, FFND, EMBED);
  pad_aout_kernel<<<(NTOK * 6 + 255) / 256, 256, 0, stream>>>(aout);

  ln_bf16_kernel<<<NTOK / 4, 256, 0, stream>>>(x, ln1g, ln1b, hb);
  mfma_gemm<EMBED / 64, EMBED * 2, EMBED * 2, 0>
      <<<dim3(NTOK / 128, QKVN / 128), 256, 0, stream>>>(
      (const char*)hb, (const char*)wqkvt, bqkv, nullptr, (char*)qkvb, QKVN);
  attn_mfma_kernel<<<BATCH * HEADS * (SEQ / 64), 256, 0, stream>>>(qkvb, aout);
  mfma_gemm<EMBED / 64, EMBED * 2, EMBED * 2, 2>
      <<<dim3(NTOK / 128, EMBED / 128), 256, 0, stream>>>(
      (const char*)aout, (const char*)wot, bo, x, (char*)x1, EMBED);
  ln_bf16_kernel<<<NTOK / 4, 256, 0, stream>>>(x1, ln2g, ln2b, h2b);
  mfma_gemm<EMBED / 64, EMBED * 2, EMBED * 2, 1>
      <<<dim3(NTOK / 128, FFND / 128), 256, 0, stream>>>(
      (const char*)h2b, (const char*)w1t, b1, nullptr, (char*)ffnb, FFND);
  mfma_gemm<FFND / 64, FFND * 2, FFND * 2, 2>
      <<<dim3(NTOK / 128, EMBED / 128), 256, 0, stream>>>(
      (const char*)ffnb, (const char*)w2t, b2, x1, (char*)out, EMBED);
}

// Round 8
// 458.640 us; speedup vs baseline: 1.0922x; 1.0922x over previous
//
#include <hip/hip_runtime.h>
#include <hip/hip_bf16.h>
#include <cmath>

#define BATCH 64
#define SEQ   512
#define EMBED 384
#define HEADS 7
#define HSZ   54
#define FFND  2304
#define NTOK  (BATCH*SEQ)
#define QKVN  1152   // 3*378 padded to 9*128
#define EPS   1e-5f
#define SCALE 0.13608276348795434f  // 54^-0.5

typedef __attribute__((ext_vector_type(8))) short s16x8;
typedef __attribute__((ext_vector_type(4))) float f32x4;

__device__ __forceinline__ ushort f2bf(float f) {
  __hip_bfloat16 h = __float2bfloat16(f);
  return *reinterpret_cast<ushort*>(&h);
}

__device__ __forceinline__ void gload16(const void* g, void* l) {
  __builtin_amdgcn_global_load_lds((const __attribute__((address_space(1))) void*)g,
                                   (__attribute__((address_space(3))) void*)l, 16, 0, 0);
}

// ---------------- LayerNorm -> bf16 out, one wave per row ----------------
__global__ __launch_bounds__(256) void ln_bf16_kernel(const float* __restrict__ x,
    const float* __restrict__ g, const float* __restrict__ b, ushort* __restrict__ out) {
  int wave = threadIdx.x >> 6, lane = threadIdx.x & 63;
  int row = (blockIdx.x << 2) + wave;
  const float* xr = x + (size_t)row * EMBED;
  float v[6]; float s = 0.f;
#pragma unroll
  for (int i = 0; i < 6; ++i) { v[i] = xr[lane + (i << 6)]; s += v[i]; }
#pragma unroll
  for (int off = 32; off; off >>= 1) s += __shfl_xor(s, off);
  float mu = s * (1.f / EMBED);
  float var = 0.f;
#pragma unroll
  for (int i = 0; i < 6; ++i) { float d = v[i] - mu; var += d * d; }
#pragma unroll
  for (int off = 32; off; off >>= 1) var += __shfl_xor(var, off);
  float rstd = rsqrtf(var * (1.f / EMBED) + EPS);
  ushort* orow = out + (size_t)row * EMBED;
#pragma unroll
  for (int i = 0; i < 6; ++i) {
    int c = lane + (i << 6);
    orow[c] = f2bf((v[i] - mu) * rstd * g[c] + b[c]);
  }
}

// ---------------- tiled transpose+convert: out[n][k] = bf16(in[k][n]), zero-padded ----------------
__global__ __launch_bounds__(256) void convT_tiled(const float* __restrict__ in,
    ushort* __restrict__ out, int K, int N, int srcK, int srcN) {
  __shared__ float t[32][33];
  int k0 = blockIdx.x << 5, n0 = blockIdx.y << 5;
  int tx = threadIdx.x & 31, ty = threadIdx.x >> 5;
#pragma unroll
  for (int i = 0; i < 4; ++i) {
    int r = ty + i * 8;
    int k = k0 + r, n = n0 + tx;
    t[r][tx] = (k < srcK && n < srcN) ? in[(size_t)k * srcN + n] : 0.f;
  }
  __syncthreads();
#pragma unroll
  for (int i = 0; i < 4; ++i) {
    int r = ty + i * 8;
    int n = n0 + r, k = k0 + tx;
    if (n < N && k < K) out[(size_t)n * K + k] = f2bf(t[tx][r]);
  }
}

// ---------------- QKV weight pack: wqkvt[n][k], n = type*378 + h*54 + hs ----------------
__global__ __launch_bounds__(256) void conv_qkvw_tiled(const float* __restrict__ wq,
    const float* __restrict__ wk, const float* __restrict__ wv, ushort* __restrict__ wt) {
  __shared__ float t[32][33];
  int k0 = blockIdx.x << 5, hs0 = blockIdx.y << 5;
  int z = blockIdx.z, type = z / 7, h = z - type * 7;
  const float* W = (type == 0) ? wq : (type == 1) ? wk : wv;
  int tx = threadIdx.x & 31, ty = threadIdx.x >> 5;
#pragma unroll
  for (int i = 0; i < 4; ++i) {
    int r = ty + i * 8;
    int k = k0 + r, hs = hs0 + tx;
    t[r][tx] = (hs < HSZ) ? W[((size_t)h * EMBED + k) * HSZ + hs] : 0.f;
  }
  __syncthreads();
#pragma unroll
  for (int i = 0; i < 4; ++i) {
    int r = ty + i * 8;
    int hs = hs0 + r, k = k0 + tx;
    if (hs < HSZ) wt[(size_t)(type * 378 + h * HSZ + hs) * EMBED + k0 + tx] = f2bf(t[tx][r]);
  }
}

// ---------------- misc fills ----------------
__global__ __launch_bounds__(256) void fill_misc(const float* __restrict__ bq,
    const float* __restrict__ bk, const float* __restrict__ bv,
    ushort* __restrict__ wt, float* __restrict__ bqkv) {
  int idx = blockIdx.x * 256 + threadIdx.x;
  if (idx < 18 * EMBED) wt[1134 * EMBED + idx] = 0;
  if (idx < QKVN) {
    float bval = 0.f;
    if (idx < 1134) {
      int type = idx / 378, rem = idx - type * 378;
      int h = rem / HSZ, hs = rem - h * HSZ;
      const float* B = (type == 0) ? bq : (type == 1) ? bk : bv;
      bval = B[h * HSZ + hs];
    }
    bqkv[idx] = bval;
  }
}

__global__ __launch_bounds__(256) void pad_aout_kernel(ushort* __restrict__ aout) {
  int idx = blockIdx.x * 256 + threadIdx.x;
  if (idx >= NTOK * 6) return;
  int row = idx / 6, c = idx - row * 6;
  aout[(size_t)row * EMBED + 378 + c] = 0;
}

// ---------------- MFMA flash attention (unchanged from round 6) ----------------
__global__ __launch_bounds__(256) void attn_mfma_kernel(const ushort* __restrict__ qkv,
    ushort* __restrict__ o) {
  __shared__ ushort Ks[2][4096];
  __shared__ ushort Vt[2][4096];
  int tid = threadIdx.x;
  int id = blockIdx.x;
  int xcd = id & 7;
  int sseq = id >> 3;
  int bh = xcd + 8 * (sseq >> 3);
  int qt = (SEQ / 64 - 1) - (sseq & 7);
  int b = bh / HEADS, h = bh - b * HEADS;
  int qr0 = qt << 6;
  int w = tid >> 6, l = tid & 63;
  int lr = l & 15, lg = l >> 4;
  const ushort* base = qkv + (size_t)b * SEQ * QKVN + h * HSZ;

  for (int e = tid; e < 64 * 5; e += 256) {
    int r = e / 5, c = 54 + 2 * (e - r * 5);
    int col = c ^ ((r & 7) << 3);
    *reinterpret_cast<uint*>(&Ks[0][r * 64 + col]) = 0;
    *reinterpret_cast<uint*>(&Ks[1][r * 64 + col]) = 0;
  }
#pragma unroll
  for (int i = 0; i < 7; ++i) {
    int e = tid + i * 256;
    int r = e / 28, c = e - r * 28;
    if (c < 27)
      *reinterpret_cast<uint*>(&Ks[1][r * 64 + ((2 * c) ^ ((r & 7) << 3))]) =
          *reinterpret_cast<const uint*>(base + (size_t)(qr0 + r) * QKVN + 2 * c);
  }
#pragma unroll
  for (int i = 0; i < 7; ++i) {
    int e = tid + i * 256;
    int k = e / 28, c = e - k * 28;
    if (c < 27)
      *reinterpret_cast<uint*>(&Ks[0][k * 64 + ((2 * c) ^ ((k & 7) << 3))]) =
          *reinterpret_cast<const uint*>(base + 378 + (size_t)k * QKVN + 2 * c);
    int ev = e >> 1, par = e & 1;
    int p = ev / 28, cv = ev - p * 28;
    uint u = (cv < 27) ? *reinterpret_cast<const uint*>(base + 756 + (size_t)(2 * p + par) * QKVN + 2 * cv) : 0u;
    uint uo = __shfl_xor(u, 1);
    if (cv < 27) {
      int k0 = 2 * p;
      int s0 = ((k0 >> 5) << 5) | (((k0 >> 2) & 3) << 3) | (((k0 >> 4) & 1) << 2) | (k0 & 3);
      int d = 2 * cv + par;
      uint wv2 = par ? ((uo >> 16) | (u & 0xffff0000u)) : ((u & 0xffffu) | (uo << 16));
      *reinterpret_cast<uint*>(&Vt[0][d * 64 + (s0 ^ ((d & 7) << 3))]) = wv2;
    }
  }
  __syncthreads();

  int qrow = w * 16 + lr;
  s16x8 qf[2];
  qf[0] = *reinterpret_cast<const s16x8*>(&Ks[1][qrow * 64 + ((8 * lg) ^ ((qrow & 7) << 3))]);
  qf[1] = *reinterpret_cast<const s16x8*>(&Ks[1][qrow * 64 + ((32 + 8 * lg) ^ ((qrow & 7) << 3))]);

  int qglob = qr0 + qrow;
  float mrow = -1e30f, lrow = 0.f;
  f32x4 acc[4];
#pragma unroll
  for (int d = 0; d < 4; ++d) acc[d] = (f32x4){0.f, 0.f, 0.f, 0.f};

  uint kreg[7], vreg[7];
  for (int kt = 0; kt <= qt; ++kt) {
    int cur = kt & 1;
    if (kt < qt) {
#pragma unroll
      for (int i = 0; i < 7; ++i) {
        int e = tid + i * 256;
        int k = e / 28, c = e - k * 28;
        kreg[i] = (c < 27) ? *reinterpret_cast<const uint*>(
            base + 378 + (size_t)((kt + 1) * 64 + k) * QKVN + 2 * c) : 0u;
        int ev = e >> 1, par = e & 1;
        int p = ev / 28, cv = ev - p * 28;
        vreg[i] = (cv < 27) ? *reinterpret_cast<const uint*>(
            base + 756 + (size_t)((kt + 1) * 64 + 2 * p + par) * QKVN + 2 * cv) : 0u;
      }
    }
    f32x4 sacc[4];
    __builtin_amdgcn_s_setprio(1);
#pragma unroll
    for (int kb = 0; kb < 4; ++kb) {
      sacc[kb] = (f32x4){0.f, 0.f, 0.f, 0.f};
#pragma unroll
      for (int h2 = 0; h2 < 2; ++h2) {
        int row = kb * 16 + lr;
        s16x8 kf = *reinterpret_cast<const s16x8*>(
            &Ks[cur][row * 64 + ((32 * h2 + 8 * lg) ^ ((row & 7) << 3))]);
        sacc[kb] = __builtin_amdgcn_mfma_f32_16x16x32_bf16(kf, qf[h2], sacc[kb], 0, 0, 0);
      }
    }
    __builtin_amdgcn_s_setprio(0);
    float sv[4][4];
    float mt = -1e30f;
    bool diag = (kt == qt);
#pragma unroll
    for (int kb = 0; kb < 4; ++kb)
#pragma unroll
      for (int r = 0; r < 4; ++r) {
        float s = sacc[kb][r] * SCALE;
        if (diag && (kt * 64 + kb * 16 + 4 * lg + r) > qglob) s = -1e30f;
        sv[kb][r] = s;
        mt = fmaxf(mt, s);
      }
    mt = fmaxf(mt, __shfl_xor(mt, 16));
    mt = fmaxf(mt, __shfl_xor(mt, 32));
    if (!__all(mt - mrow <= 8.f)) {
      float mnew = fmaxf(mrow, mt);
      float al = __expf(mrow - mnew);
#pragma unroll
      for (int d = 0; d < 4; ++d)
#pragma unroll
        for (int r = 0; r < 4; ++r) acc[d][r] *= al;
      lrow *= al;
      mrow = mnew;
    }
    float lsum = 0.f;
    short p16[4][4];
#pragma unroll
    for (int kb = 0; kb < 4; ++kb)
#pragma unroll
      for (int r = 0; r < 4; ++r) {
        float p = __expf(sv[kb][r] - mrow);
        lsum += p;
        p16[kb][r] = (short)f2bf(p);
      }
    lrow += lsum;
    s16x8 af[2];
#pragma unroll
    for (int m = 0; m < 2; ++m)
#pragma unroll
      for (int j = 0; j < 8; ++j) af[m][j] = p16[2 * m + (j >> 2)][j & 3];
    __builtin_amdgcn_s_setprio(1);
#pragma unroll
    for (int m = 0; m < 2; ++m)
#pragma unroll
      for (int d = 0; d < 4; ++d) {
        int row = d * 16 + lr;
        s16x8 vf = *reinterpret_cast<const s16x8*>(
            &Vt[cur][row * 64 + ((32 * m + 8 * lg) ^ ((row & 7) << 3))]);
        acc[d] = __builtin_amdgcn_mfma_f32_16x16x32_bf16(vf, af[m], acc[d], 0, 0, 0);
      }
    __builtin_amdgcn_s_setprio(0);
    if (kt < qt) {
      __syncthreads();
      int nxt = cur ^ 1;
#pragma unroll
      for (int i = 0; i < 7; ++i) {
        int e = tid + i * 256;
        int k = e / 28, c = e - k * 28;
        if (c < 27)
          *reinterpret_cast<uint*>(&Ks[nxt][k * 64 + ((2 * c) ^ ((k & 7) << 3))]) = kreg[i];
        int ev = e >> 1, par = e & 1;
        int p = ev / 28, cv = ev - p * 28;
        uint u = vreg[i];
        uint uo = __shfl_xor(u, 1);
        if (cv < 27) {
          int k0 = 2 * p;
          int s0 = ((k0 >> 5) << 5) | (((k0 >> 2) & 3) << 3) | (((k0 >> 4) & 1) << 2) | (k0 & 3);
          int d = 2 * cv + par;
          uint wv2 = par ? ((uo >> 16) | (u & 0xffff0000u)) : ((u & 0xffffu) | (uo << 16));
          *reinterpret_cast<uint*>(&Vt[nxt][d * 64 + (s0 ^ ((d & 7) << 3))]) = wv2;
        }
      }
      __syncthreads();
    }
  }

  lrow += __shfl_xor(lrow, 16);
  lrow += __shfl_xor(lrow, 32);
  float linv = 1.f / lrow;
  __syncthreads();
  ushort* Olds = &Ks[0][0];
#pragma unroll
  for (int d = 0; d < 4; ++d)
#pragma unroll
    for (int r = 0; r < 4; ++r)
      Olds[(d * 16 + 4 * lg + r) * 64 + w * 16 + lr] = f2bf(acc[d][r] * linv);
  __syncthreads();
  for (int e = tid; e < 64 * 27; e += 256) {
    int q = e / 27, c = e - q * 27;
    uint lo = Olds[(2 * c) * 64 + q];
    uint hi = Olds[(2 * c + 1) * 64 + q];
    *reinterpret_cast<uint*>(&o[(size_t)(b * SEQ + qr0 + q) * EMBED + h * HSZ + 2 * c]) =
        lo | (hi << 16);
  }
}

// ---------------- bf16 MFMA GEMM: 128x128 tile, BK=64, 4 waves, 2-PHASE PREFETCH ----------------
// Double-buffered LDS (64 KB): As0 [0,8192) As1 [8192,16384) Bs0 [16384,24576) Bs1 [24576,32768)
// (ushort indices). Per iteration: issue STAGE(t+1, other buf) -> compute(t) -> one barrier.
// MODE 0: C = bf16(A@B + bias)   MODE 1: C = bf16(fast_gelu(A@B + bias))
// MODE 2: C = f32(A@B + bias + resid)
template<int KSTEPS, int LDA, int LDB, int MODE>
__global__ __launch_bounds__(256) void mfma_gemm(
    const char* __restrict__ Ab, const char* __restrict__ Btb,
    const float* __restrict__ bias, const float* __restrict__ resid,
    char* __restrict__ Cb, int ncols) {
  __shared__ ushort sh[32768];
  int tid = threadIdx.x;
  int wv = tid >> 6, l = tid & 63;
  int wr = wv >> 1, wc = wv & 1;
  int lr = l & 15, lg = l >> 4;
  int tok0 = blockIdx.x << 7;
  int col0 = blockIdx.y << 7;

  const char* aptr[4]; const char* bptr[4];
#pragma unroll
  for (int is = 0; is < 4; ++is) {
    int i = is * 256 + tid;
    int row = i >> 3;
    int boff = (i & 7) << 4;
    int sw = boff ^ ((row & 7) << 4);
    aptr[is] = Ab + (size_t)(tok0 + row) * LDA + sw;
    bptr[is] = Btb + (size_t)(col0 + row) * LDB + sw;
  }

  int offA[2][4], offB[2][4];   // ushort offsets within one 8192-entry buffer
#pragma unroll
  for (int m = 0; m < 4; ++m) {
    int rowa = wr * 64 + m * 16 + lr;
    int rowb = wc * 64 + m * 16 + lr;
    int sa = (rowa & 7) << 4, sb = (rowb & 7) << 4;
#pragma unroll
    for (int kk = 0; kk < 2; ++kk) {
      int kb = kk * 64 + lg * 16;
      offA[kk][m] = (rowa * 128 + (kb ^ sa)) >> 1;
      offB[kk][m] = (rowb * 128 + (kb ^ sb)) >> 1;
    }
  }

  f32x4 acc[4][4];
#pragma unroll
  for (int m = 0; m < 4; ++m)
#pragma unroll
    for (int n = 0; n < 4; ++n) acc[m][n] = (f32x4){0.f, 0.f, 0.f, 0.f};

  // prologue: stage tile 0 into buffer 0
#pragma unroll
  for (int is = 0; is < 4; ++is) {
    gload16(aptr[is], (char*)sh + is * 4096 + wv * 1024);
    gload16(bptr[is], (char*)sh + 32768 + is * 4096 + wv * 1024);
  }
  __syncthreads();

  for (int ks = 0; ks < KSTEPS; ++ks) {
    int buf = ks & 1;
    if (ks + 1 < KSTEPS) {   // issue next tile's loads into the other buffer
      int nb = buf ^ 1;
#pragma unroll
      for (int is = 0; is < 4; ++is) {
        gload16(aptr[is] + (size_t)(ks + 1) * 128, (char*)sh + nb * 16384 + is * 4096 + wv * 1024);
        gload16(bptr[is] + (size_t)(ks + 1) * 128, (char*)sh + 32768 + nb * 16384 + is * 4096 + wv * 1024);
      }
    }
    int ao = buf * 8192, bo = 16384 + buf * 8192;
    __builtin_amdgcn_s_setprio(1);
#pragma unroll
    for (int kk = 0; kk < 2; ++kk) {
      s16x8 af[4], bfr[4];
#pragma unroll
      for (int m = 0; m < 4; ++m) af[m] = *reinterpret_cast<const s16x8*>(&sh[ao + offA[kk][m]]);
#pragma unroll
      for (int n = 0; n < 4; ++n) bfr[n] = *reinterpret_cast<const s16x8*>(&sh[bo + offB[kk][n]]);
#pragma unroll
      for (int m = 0; m < 4; ++m)
#pragma unroll
        for (int n = 0; n < 4; ++n)
          acc[m][n] = __builtin_amdgcn_mfma_f32_16x16x32_bf16(af[m], bfr[n], acc[m][n], 0, 0, 0);
    }
    __builtin_amdgcn_s_setprio(0);
    if (ks + 1 < KSTEPS) __syncthreads();  // drains vmcnt: next tile resident; cur tile consumed
  }

  float bn[4];
  int colr = col0 + wc * 64 + lr;
#pragma unroll
  for (int n = 0; n < 4; ++n) bn[n] = bias[colr + n * 16];

  if constexpr (MODE == 2) {
    int tokr = tok0 + wr * 64 + lg * 4;
    float* C = (float*)Cb;
#pragma unroll
    for (int m = 0; m < 4; ++m)
#pragma unroll
      for (int r = 0; r < 4; ++r) {
        size_t rowbase = (size_t)(tokr + m * 16 + r) * ncols;
#pragma unroll
        for (int n = 0; n < 4; ++n) {
          size_t idx = rowbase + colr + n * 16;
          C[idx] = acc[m][n][r] + bn[n] + resid[idx];
        }
      }
  } else {
    // LDS-bounce epilogue in sh[0:16384): [128][128] bf16,
    // physical col = col ^ (((row>>2)&3)<<4) — conflict-free both sides
    __syncthreads();   // all waves done with K-loop LDS before overwrite
#pragma unroll
    for (int m = 0; m < 4; ++m)
#pragma unroll
      for (int r = 0; r < 4; ++r) {
        int row = wr * 64 + m * 16 + lg * 4 + r;
        int rmask = ((row >> 2) & 3) << 4;
#pragma unroll
        for (int n = 0; n < 4; ++n) {
          float xg = acc[m][n][r] + bn[n];
          if constexpr (MODE == 1) {
            float u2 = xg * (1.5957691216f + 0.0713548162f * xg * xg);
            xg = xg * __builtin_amdgcn_rcpf(1.f + __expf(-u2));
          }
          int col = wc * 64 + n * 16 + lr;
          sh[row * 128 + (col ^ rmask)] = f2bf(xg);
        }
      }
    __syncthreads();
    ushort* C = (ushort*)Cb;
    int blk = (l & 7) + 8 * (wv & 1);
    int rbase = (l >> 3) + 64 * (wv >> 1);
#pragma unroll
    for (int it = 0; it < 8; ++it) {
      int row = rbase + 8 * it;
      int pblk = blk ^ (((row >> 2) & 3) << 1);
      uint4 vv = *reinterpret_cast<const uint4*>(&sh[row * 128 + pblk * 8]);
      *reinterpret_cast<uint4*>(&C[(size_t)(tok0 + row) * ncols + col0 + blk * 8]) = vv;
    }
  }
}

extern "C" void kernel_launch(void* const* d_in, const int* in_sizes, int n_in,
                              void* d_out, int out_size, void* d_ws, size_t ws_size,
                              hipStream_t stream) {
  const float* x    = (const float*)d_in[0];
  const float* wq   = (const float*)d_in[1];
  const float* bq   = (const float*)d_in[2];
  const float* wk   = (const float*)d_in[3];
  const float* bk   = (const float*)d_in[4];
  const float* wv   = (const float*)d_in[5];
  const float* bv   = (const float*)d_in[6];
  const float* wo   = (const float*)d_in[7];
  const float* bo   = (const float*)d_in[8];
  const float* w1   = (const float*)d_in[9];
  const float* b1   = (const float*)d_in[10];
  const float* w2   = (const float*)d_in[11];
  const float* b2   = (const float*)d_in[12];
  const float* ln1g = (const float*)d_in[13];
  const float* ln1b = (const float*)d_in[14];
  const float* ln2g = (const float*)d_in[15];
  const float* ln2b = (const float*)d_in[16];
  float* out = (float*)d_out;

  char* wsb = (char*)d_ws;
  float*  x1    = (float*)wsb;
  ushort* ffnb  = (ushort*)(wsb + 50331648);
  ushort* hb    = (ushort*)(wsb + 50331648);
  ushort* qkvb  = (ushort*)(wsb + 75497472);
  ushort* aout  = (ushort*)(wsb + 150994944);
  ushort* h2b   = (ushort*)(wsb + 201326592);
  ushort* w1t   = (ushort*)(wsb + 226492416);
  ushort* w2t   = (ushort*)(wsb + 228261888);
  ushort* wqkvt = (ushort*)(wsb + 230031360);
  ushort* wot   = (ushort*)(wsb + 230916096);
  float*  bqkv  = (float*)(wsb + 231211008);

  conv_qkvw_tiled<<<dim3(12, 2, 21), 256, 0, stream>>>(wq, wk, wv, wqkvt);
  fill_misc      <<<27, 256, 0, stream>>>(bq, bk, bv, wqkvt, bqkv);
  convT_tiled    <<<dim3(12, 12), 256, 0, stream>>>(wo, wot, EMBED, EMBED, 378, EMBED);
  convT_tiled    <<<dim3(12, 72), 256, 0, stream>>>(w1, w1t, EMBED, FFND, EMBED, FFND);
  convT_tiled    <<<dim3(72, 12), 256, 0, stream>>>(w2, w2t, FFND, EMBED, FFND, EMBED);
  pad_aout_kernel<<<(NTOK * 6 + 255) / 256, 256, 0, stream>>>(aout);

  ln_bf16_kernel<<<NTOK / 4, 256, 0, stream>>>(x, ln1g, ln1b, hb);
  mfma_gemm<EMBED / 64, EMBED * 2, EMBED * 2, 0>
      <<<dim3(NTOK / 128, QKVN / 128), 256, 0, stream>>>(
      (const char*)hb, (const char*)wqkvt, bqkv, nullptr, (char*)qkvb, QKVN);
  attn_mfma_kernel<<<BATCH * HEADS * (SEQ / 64), 256, 0, stream>>>(qkvb, aout);
  mfma_gemm<EMBED / 64, EMBED * 2, EMBED * 2, 2>
      <<<dim3(NTOK / 128, EMBED / 128), 256, 0, stream>>>(
      (const char*)aout, (const char*)wot, bo, x, (char*)x1, EMBED);
  ln_bf16_kernel<<<NTOK / 4, 256, 0, stream>>>(x1, ln2g, ln2b, h2b);
  mfma_gemm<EMBED / 64, EMBED * 2, EMBED * 2, 1>
      <<<dim3(NTOK / 128, FFND / 128), 256, 0, stream>>>(
      (const char*)h2b, (const char*)w1t, b1, nullptr, (char*)ffnb, FFND);
  mfma_gemm<FFND / 64, FFND * 2, FFND * 2, 2>
      <<<dim3(NTOK / 128, EMBED / 128), 256, 0, stream>>>(
      (const char*)ffnb, (const char*)w2t, b2, x1, (char*)out, EMBED);
}

// Round 9
// 446.641 us; speedup vs baseline: 1.1215x; 1.0269x over previous
//
#include <hip/hip_runtime.h>
#include <hip/hip_bf16.h>
#include <cmath>

#define BATCH 64
#define SEQ   512
#define EMBED 384
#define HEADS 7
#define HSZ   54
#define FFND  2304
#define NTOK  (BATCH*SEQ)
#define QKVN  1152   // 3*378 padded to 9*128
#define EPS   1e-5f
#define SCALE 0.13608276348795434f  // 54^-0.5

typedef __attribute__((ext_vector_type(8))) short s16x8;
typedef __attribute__((ext_vector_type(4))) float f32x4;

__device__ __forceinline__ ushort f2bf(float f) {
  __hip_bfloat16 h = __float2bfloat16(f);
  return *reinterpret_cast<ushort*>(&h);
}

__device__ __forceinline__ void gload16(const void* g, void* l) {
  __builtin_amdgcn_global_load_lds((const __attribute__((address_space(1))) void*)g,
                                   (__attribute__((address_space(3))) void*)l, 16, 0, 0);
}

// ---------------- LayerNorm -> bf16 out, one wave per row ----------------
__global__ __launch_bounds__(256) void ln_bf16_kernel(const float* __restrict__ x,
    const float* __restrict__ g, const float* __restrict__ b, ushort* __restrict__ out) {
  int wave = threadIdx.x >> 6, lane = threadIdx.x & 63;
  int row = (blockIdx.x << 2) + wave;
  const float* xr = x + (size_t)row * EMBED;
  float v[6]; float s = 0.f;
#pragma unroll
  for (int i = 0; i < 6; ++i) { v[i] = xr[lane + (i << 6)]; s += v[i]; }
#pragma unroll
  for (int off = 32; off; off >>= 1) s += __shfl_xor(s, off);
  float mu = s * (1.f / EMBED);
  float var = 0.f;
#pragma unroll
  for (int i = 0; i < 6; ++i) { float d = v[i] - mu; var += d * d; }
#pragma unroll
  for (int off = 32; off; off >>= 1) var += __shfl_xor(var, off);
  float rstd = rsqrtf(var * (1.f / EMBED) + EPS);
  ushort* orow = out + (size_t)row * EMBED;
#pragma unroll
  for (int i = 0; i < 6; ++i) {
    int c = lane + (i << 6);
    orow[c] = f2bf((v[i] - mu) * rstd * g[c] + b[c]);
  }
}

// ---------------- tiled transpose+convert: out[n][k] = bf16(in[k][n]), zero-padded ----------------
__global__ __launch_bounds__(256) void convT_tiled(const float* __restrict__ in,
    ushort* __restrict__ out, int K, int N, int srcK, int srcN) {
  __shared__ float t[32][33];
  int k0 = blockIdx.x << 5, n0 = blockIdx.y << 5;
  int tx = threadIdx.x & 31, ty = threadIdx.x >> 5;
#pragma unroll
  for (int i = 0; i < 4; ++i) {
    int r = ty + i * 8;
    int k = k0 + r, n = n0 + tx;
    t[r][tx] = (k < srcK && n < srcN) ? in[(size_t)k * srcN + n] : 0.f;
  }
  __syncthreads();
#pragma unroll
  for (int i = 0; i < 4; ++i) {
    int r = ty + i * 8;
    int n = n0 + r, k = k0 + tx;
    if (n < N && k < K) out[(size_t)n * K + k] = f2bf(t[tx][r]);
  }
}

// ---------------- QKV weight pack: wqkvt[n][k], n = type*378 + h*54 + hs ----------------
__global__ __launch_bounds__(256) void conv_qkvw_tiled(const float* __restrict__ wq,
    const float* __restrict__ wk, const float* __restrict__ wv, ushort* __restrict__ wt) {
  __shared__ float t[32][33];
  int k0 = blockIdx.x << 5, hs0 = blockIdx.y << 5;
  int z = blockIdx.z, type = z / 7, h = z - type * 7;
  const float* W = (type == 0) ? wq : (type == 1) ? wk : wv;
  int tx = threadIdx.x & 31, ty = threadIdx.x >> 5;
#pragma unroll
  for (int i = 0; i < 4; ++i) {
    int r = ty + i * 8;
    int k = k0 + r, hs = hs0 + tx;
    t[r][tx] = (hs < HSZ) ? W[((size_t)h * EMBED + k) * HSZ + hs] : 0.f;
  }
  __syncthreads();
#pragma unroll
  for (int i = 0; i < 4; ++i) {
    int r = ty + i * 8;
    int hs = hs0 + r, k = k0 + tx;
    if (hs < HSZ) wt[(size_t)(type * 378 + h * HSZ + hs) * EMBED + k0 + tx] = f2bf(t[tx][r]);
  }
}

// ---------------- misc fills ----------------
__global__ __launch_bounds__(256) void fill_misc(const float* __restrict__ bq,
    const float* __restrict__ bk, const float* __restrict__ bv,
    ushort* __restrict__ wt, float* __restrict__ bqkv) {
  int idx = blockIdx.x * 256 + threadIdx.x;
  if (idx < 18 * EMBED) wt[1134 * EMBED + idx] = 0;
  if (idx < QKVN) {
    float bval = 0.f;
    if (idx < 1134) {
      int type = idx / 378, rem = idx - type * 378;
      int h = rem / HSZ, hs = rem - h * HSZ;
      const float* B = (type == 0) ? bq : (type == 1) ? bk : bv;
      bval = B[h * HSZ + hs];
    }
    bqkv[idx] = bval;
  }
}

__global__ __launch_bounds__(256) void pad_aout_kernel(ushort* __restrict__ aout) {
  int idx = blockIdx.x * 256 + threadIdx.x;
  if (idx >= NTOK * 6) return;
  int row = idx / 6, c = idx - row * 6;
  aout[(size_t)row * EMBED + 378 + c] = 0;
}

// ---------------- MFMA flash attention (hoisted staging, gload K, 1 barrier/tile) ----------------
// 1D grid 3584: xcd=id&7, bh=xcd+8*(id>>6), qt=7-((id>>3)&7) — same-bh on same XCD, heavy first.
// K tiles staged by global_load_lds with pre-swizzled global source (K pad cols 54..63 hold
// garbage neighbor-head values — safe because Q pads are zeroed, 0*garbage = 0).
// V transpose-staged via regs with geometry hoisted out of the loop.
// S^T = mfma(K,Q): C[key=16kb+4lg+r][q=lr]; P lane-local -> B-frag of O^T = mfma(V^T,P).
// slot perm: key k = 32m+16b+4g+r <-> slot 32m+8g+4b+r. LDS rows 64 ushorts,
// chunk-XOR swizzle: phys chunk = logical chunk ^ (row&7).
__global__ __launch_bounds__(256) void attn_mfma_kernel(const ushort* __restrict__ qkv,
    ushort* __restrict__ o) {
  __shared__ ushort Ks[2][4096];
  __shared__ ushort Vt[2][4096];
  int tid = threadIdx.x;
  int id = blockIdx.x;
  int xcd = id & 7;
  int sseq = id >> 3;
  int bh = xcd + 8 * (sseq >> 3);
  int qt = (SEQ / 64 - 1) - (sseq & 7);
  int b = bh / HEADS, h = bh - b * HEADS;
  int qr0 = qt << 6;
  int w = tid >> 6, l = tid & 63;
  int lr = l & 15, lg = l >> 4;
  const ushort* base = qkv + (size_t)b * SEQ * QKVN + h * HSZ;
  const size_t TSTR = (size_t)64 * QKVN * 2;   // bytes per KV tile step

  // ---- staging geometry (computed ONCE) ----
  // gload lanes: row = w*8 + (l>>3) (+32 for pass 1), logical chunk = (l&7)^(l>>3)
  int grow = w * 8 + (l >> 3);
  int gc = (l & 7) ^ (l >> 3);
  const char* kg0 = (const char*)(base + 378 + (size_t)grow * QKVN + gc * 8);
  const char* kg1 = (const char*)(base + 378 + (size_t)(grow + 32) * QKVN + gc * 8);
  const char* qg0 = (const char*)(base + (size_t)(qr0 + grow) * QKVN + gc * 8);
  const char* qg1 = (const char*)(base + (size_t)(qr0 + grow + 32) * QKVN + gc * 8);
  // V path: per i, fixed (dst, src-offset, parity)
  int vdst[7]; const char* vsrc[7]; bool vpar[7];
#pragma unroll
  for (int i = 0; i < 7; ++i) {
    int e = tid + i * 256;
    int ev = e >> 1, par = e & 1;
    int p = ev / 28, cv = ev - p * 28;
    if (cv < 27) {
      int k0 = 2 * p;
      int s0 = ((k0 >> 5) << 5) | (((k0 >> 2) & 3) << 3) | (((k0 >> 4) & 1) << 2) | (k0 & 3);
      int d = 2 * cv + par;
      vdst[i] = d * 64 + (s0 ^ ((d & 7) << 3));
      vsrc[i] = (const char*)(base + 756 + (size_t)(2 * p + par) * QKVN + 2 * cv);
      vpar[i] = (par != 0);
    } else { vdst[i] = -1; vsrc[i] = (const char*)base; vpar[i] = false; }
  }

  // ---- prologue: Q -> Ks[1], K0 -> Ks[0] (gload), V0 -> regs ----
  gload16(qg0, (char*)&Ks[1][0] + w * 1024);
  gload16(qg1, (char*)&Ks[1][0] + 4096 + w * 1024);
  gload16(kg0, (char*)&Ks[0][0] + w * 1024);
  gload16(kg1, (char*)&Ks[0][0] + 4096 + w * 1024);
  uint uv[7];
#pragma unroll
  for (int i = 0; i < 7; ++i)
    uv[i] = (vdst[i] >= 0) ? *reinterpret_cast<const uint*>(vsrc[i]) : 0u;
  __syncthreads();   // gloads + v loads complete
  // zero Q pad cols 54..63 (5 uint-slots per row, swizzle-aware) + commit V0
  for (int e = tid; e < 320; e += 256) {
    int r = e / 5, which = e - r * 5;
    int idx = (which == 0) ? (r * 64 + ((6 ^ (r & 7)) << 3) + 6)
                           : (r * 64 + ((7 ^ (r & 7)) << 3) + 2 * (which - 1));
    *reinterpret_cast<uint*>(&Ks[1][idx]) = 0;
  }
#pragma unroll
  for (int i = 0; i < 7; ++i) {
    uint u = uv[i]; uint uo = __shfl_xor(u, 1);
    if (vdst[i] >= 0) {
      uint wv2 = vpar[i] ? ((uo >> 16) | (u & 0xffff0000u)) : ((u & 0xffffu) | (uo << 16));
      *reinterpret_cast<uint*>(&Vt[0][vdst[i]]) = wv2;
    }
  }
  __syncthreads();
  int qrow = w * 16 + lr;
  s16x8 qf[2];
  qf[0] = *reinterpret_cast<const s16x8*>(&Ks[1][qrow * 64 + ((8 * lg) ^ ((qrow & 7) << 3))]);
  qf[1] = *reinterpret_cast<const s16x8*>(&Ks[1][qrow * 64 + ((32 + 8 * lg) ^ ((qrow & 7) << 3))]);
  __syncthreads();   // all waves read Q before tile-1 gload may overwrite Ks[1]

  int qglob = qr0 + qrow;
  float mrow = -1e30f, lrow = 0.f;
  f32x4 acc[4];
#pragma unroll
  for (int d = 0; d < 4; ++d) acc[d] = (f32x4){0.f, 0.f, 0.f, 0.f};

  for (int kt = 0; kt <= qt; ++kt) {
    int cur = kt & 1, nxt = cur ^ 1;
    if (kt < qt) {  // issue next tile: K via gload_lds, V into regs
      kg0 += TSTR; kg1 += TSTR;
      gload16(kg0, (char*)&Ks[nxt][0] + w * 1024);
      gload16(kg1, (char*)&Ks[nxt][0] + 4096 + w * 1024);
#pragma unroll
      for (int i = 0; i < 7; ++i) {
        vsrc[i] += TSTR;
        if (vdst[i] >= 0) uv[i] = *reinterpret_cast<const uint*>(vsrc[i]);
      }
    }
    // S^T = K @ Q^T
    f32x4 sacc[4];
    __builtin_amdgcn_s_setprio(1);
#pragma unroll
    for (int kb = 0; kb < 4; ++kb) {
      sacc[kb] = (f32x4){0.f, 0.f, 0.f, 0.f};
#pragma unroll
      for (int h2 = 0; h2 < 2; ++h2) {
        int row = kb * 16 + lr;
        s16x8 kf = *reinterpret_cast<const s16x8*>(
            &Ks[cur][row * 64 + ((32 * h2 + 8 * lg) ^ ((row & 7) << 3))]);
        sacc[kb] = __builtin_amdgcn_mfma_f32_16x16x32_bf16(kf, qf[h2], sacc[kb], 0, 0, 0);
      }
    }
    __builtin_amdgcn_s_setprio(0);
    // scale + causal + online softmax (q = lr lane-local)
    float sv[4][4];
    float mt = -1e30f;
    bool diag = (kt == qt);
#pragma unroll
    for (int kb = 0; kb < 4; ++kb)
#pragma unroll
      for (int r = 0; r < 4; ++r) {
        float s = sacc[kb][r] * SCALE;
        if (diag && (kt * 64 + kb * 16 + 4 * lg + r) > qglob) s = -1e30f;
        sv[kb][r] = s;
        mt = fmaxf(mt, s);
      }
    mt = fmaxf(mt, __shfl_xor(mt, 16));
    mt = fmaxf(mt, __shfl_xor(mt, 32));
    if (!__all(mt - mrow <= 8.f)) {   // defer-max
      float mnew = fmaxf(mrow, mt);
      float al = __expf(mrow - mnew);
#pragma unroll
      for (int d = 0; d < 4; ++d)
#pragma unroll
        for (int r = 0; r < 4; ++r) acc[d][r] *= al;
      lrow *= al;
      mrow = mnew;
    }
    union { short s[16]; s16x8 v[2]; } pp;
    float lsum = 0.f;
#pragma unroll
    for (int kb = 0; kb < 4; ++kb)
#pragma unroll
      for (int r = 0; r < 4; ++r) {
        float p = __expf(sv[kb][r] - mrow);
        lsum += p;
        pp.s[kb * 4 + r] = (short)f2bf(p);
      }
    lrow += lsum;
    // O^T += V^T @ P^T  (P = pp.v[m] directly: af[m][j] = p16[2m+(j>>2)][j&3])
    __builtin_amdgcn_s_setprio(1);
#pragma unroll
    for (int m = 0; m < 2; ++m)
#pragma unroll
      for (int d = 0; d < 4; ++d) {
        int row = d * 16 + lr;
        s16x8 vf = *reinterpret_cast<const s16x8*>(
            &Vt[cur][row * 64 + ((32 * m + 8 * lg) ^ ((row & 7) << 3))]);
        acc[d] = __builtin_amdgcn_mfma_f32_16x16x32_bf16(vf, pp.v[m], acc[d], 0, 0, 0);
      }
    __builtin_amdgcn_s_setprio(0);
    if (kt < qt) {
      // commit V(t+1) regs -> Vt[nxt]  (safe: all waves passed previous barrier)
#pragma unroll
      for (int i = 0; i < 7; ++i) {
        uint u = uv[i]; uint uo = __shfl_xor(u, 1);
        if (vdst[i] >= 0) {
          uint wv2 = vpar[i] ? ((uo >> 16) | (u & 0xffff0000u)) : ((u & 0xffffu) | (uo << 16));
          *reinterpret_cast<uint*>(&Vt[nxt][vdst[i]]) = wv2;
        }
      }
      __syncthreads();  // drains vmcnt (K gload) + lgkm (V commit); buffers ready
    }
  }

  lrow += __shfl_xor(lrow, 16);
  lrow += __shfl_xor(lrow, 32);
  float linv = 1.f / lrow;
  __syncthreads();
  ushort* Olds = &Ks[0][0];   // reuse: [d][q], stride 64
#pragma unroll
  for (int d = 0; d < 4; ++d)
#pragma unroll
    for (int r = 0; r < 4; ++r)
      Olds[(d * 16 + 4 * lg + r) * 64 + w * 16 + lr] = f2bf(acc[d][r] * linv);
  __syncthreads();
  for (int e = tid; e < 64 * 27; e += 256) {
    int q = e / 27, c = e - q * 27;
    uint lo = Olds[(2 * c) * 64 + q];
    uint hi = Olds[(2 * c + 1) * 64 + q];
    *reinterpret_cast<uint*>(&o[(size_t)(b * SEQ + qr0 + q) * EMBED + h * HSZ + 2 * c]) =
        lo | (hi << 16);
  }
}

// ---------------- bf16 MFMA GEMM: 128x128 tile, BK=64, 4 waves, 2-PHASE PREFETCH ----------------
// MODE 0: C = bf16(A@B + bias)   MODE 1: C = bf16(fast_gelu(A@B + bias))
// MODE 2: C = f32(A@B + bias + resid)
template<int KSTEPS, int LDA, int LDB, int MODE>
__global__ __launch_bounds__(256) void mfma_gemm(
    const char* __restrict__ Ab, const char* __restrict__ Btb,
    const float* __restrict__ bias, const float* __restrict__ resid,
    char* __restrict__ Cb, int ncols) {
  __shared__ ushort sh[32768];
  int tid = threadIdx.x;
  int wv = tid >> 6, l = tid & 63;
  int wr = wv >> 1, wc = wv & 1;
  int lr = l & 15, lg = l >> 4;
  int tok0 = blockIdx.x << 7;
  int col0 = blockIdx.y << 7;

  const char* aptr[4]; const char* bptr[4];
#pragma unroll
  for (int is = 0; is < 4; ++is) {
    int i = is * 256 + tid;
    int row = i >> 3;
    int boff = (i & 7) << 4;
    int sw = boff ^ ((row & 7) << 4);
    aptr[is] = Ab + (size_t)(tok0 + row) * LDA + sw;
    bptr[is] = Btb + (size_t)(col0 + row) * LDB + sw;
  }

  int offA[2][4], offB[2][4];
#pragma unroll
  for (int m = 0; m < 4; ++m) {
    int rowa = wr * 64 + m * 16 + lr;
    int rowb = wc * 64 + m * 16 + lr;
    int sa = (rowa & 7) << 4, sb = (rowb & 7) << 4;
#pragma unroll
    for (int kk = 0; kk < 2; ++kk) {
      int kb = kk * 64 + lg * 16;
      offA[kk][m] = (rowa * 128 + (kb ^ sa)) >> 1;
      offB[kk][m] = (rowb * 128 + (kb ^ sb)) >> 1;
    }
  }

  f32x4 acc[4][4];
#pragma unroll
  for (int m = 0; m < 4; ++m)
#pragma unroll
    for (int n = 0; n < 4; ++n) acc[m][n] = (f32x4){0.f, 0.f, 0.f, 0.f};

#pragma unroll
  for (int is = 0; is < 4; ++is) {
    gload16(aptr[is], (char*)sh + is * 4096 + wv * 1024);
    gload16(bptr[is], (char*)sh + 32768 + is * 4096 + wv * 1024);
  }
  __syncthreads();

  for (int ks = 0; ks < KSTEPS; ++ks) {
    int buf = ks & 1;
    if (ks + 1 < KSTEPS) {
      int nb = buf ^ 1;
#pragma unroll
      for (int is = 0; is < 4; ++is) {
        gload16(aptr[is] + (size_t)(ks + 1) * 128, (char*)sh + nb * 16384 + is * 4096 + wv * 1024);
        gload16(bptr[is] + (size_t)(ks + 1) * 128, (char*)sh + 32768 + nb * 16384 + is * 4096 + wv * 1024);
      }
    }
    int ao = buf * 8192, bo = 16384 + buf * 8192;
    __builtin_amdgcn_s_setprio(1);
#pragma unroll
    for (int kk = 0; kk < 2; ++kk) {
      s16x8 af[4], bfr[4];
#pragma unroll
      for (int m = 0; m < 4; ++m) af[m] = *reinterpret_cast<const s16x8*>(&sh[ao + offA[kk][m]]);
#pragma unroll
      for (int n = 0; n < 4; ++n) bfr[n] = *reinterpret_cast<const s16x8*>(&sh[bo + offB[kk][n]]);
#pragma unroll
      for (int m = 0; m < 4; ++m)
#pragma unroll
        for (int n = 0; n < 4; ++n)
          acc[m][n] = __builtin_amdgcn_mfma_f32_16x16x32_bf16(af[m], bfr[n], acc[m][n], 0, 0, 0);
    }
    __builtin_amdgcn_s_setprio(0);
    if (ks + 1 < KSTEPS) __syncthreads();
  }

  float bn[4];
  int colr = col0 + wc * 64 + lr;
#pragma unroll
  for (int n = 0; n < 4; ++n) bn[n] = bias[colr + n * 16];

  if constexpr (MODE == 2) {
    int tokr = tok0 + wr * 64 + lg * 4;
    float* C = (float*)Cb;
#pragma unroll
    for (int m = 0; m < 4; ++m)
#pragma unroll
      for (int r = 0; r < 4; ++r) {
        size_t rowbase = (size_t)(tokr + m * 16 + r) * ncols;
#pragma unroll
        for (int n = 0; n < 4; ++n) {
          size_t idx = rowbase + colr + n * 16;
          C[idx] = acc[m][n][r] + bn[n] + resid[idx];
        }
      }
  } else {
    __syncthreads();
#pragma unroll
    for (int m = 0; m < 4; ++m)
#pragma unroll
      for (int r = 0; r < 4; ++r) {
        int row = wr * 64 + m * 16 + lg * 4 + r;
        int rmask = ((row >> 2) & 3) << 4;
#pragma unroll
        for (int n = 0; n < 4; ++n) {
          float xg = acc[m][n][r] + bn[n];
          if constexpr (MODE == 1) {
            float u2 = xg * (1.5957691216f + 0.0713548162f * xg * xg);
            xg = xg * __builtin_amdgcn_rcpf(1.f + __expf(-u2));
          }
          int col = wc * 64 + n * 16 + lr;
          sh[row * 128 + (col ^ rmask)] = f2bf(xg);
        }
      }
    __syncthreads();
    ushort* C = (ushort*)Cb;
    int blk = (l & 7) + 8 * (wv & 1);
    int rbase = (l >> 3) + 64 * (wv >> 1);
#pragma unroll
    for (int it = 0; it < 8; ++it) {
      int row = rbase + 8 * it;
      int pblk = blk ^ (((row >> 2) & 3) << 1);
      uint4 vvv = *reinterpret_cast<const uint4*>(&sh[row * 128 + pblk * 8]);
      *reinterpret_cast<uint4*>(&C[(size_t)(tok0 + row) * ncols + col0 + blk * 8]) = vvv;
    }
  }
}

extern "C" void kernel_launch(void* const* d_in, const int* in_sizes, int n_in,
                              void* d_out, int out_size, void* d_ws, size_t ws_size,
                              hipStream_t stream) {
  const float* x    = (const float*)d_in[0];
  const float* wq   = (const float*)d_in[1];
  const float* bq   = (const float*)d_in[2];
  const float* wk   = (const float*)d_in[3];
  const float* bk   = (const float*)d_in[4];
  const float* wv   = (const float*)d_in[5];
  const float* bv   = (const float*)d_in[6];
  const float* wo   = (const float*)d_in[7];
  const float* bo   = (const float*)d_in[8];
  const float* w1   = (const float*)d_in[9];
  const float* b1   = (const float*)d_in[10];
  const float* w2   = (const float*)d_in[11];
  const float* b2   = (const float*)d_in[12];
  const float* ln1g = (const float*)d_in[13];
  const float* ln1b = (const float*)d_in[14];
  const float* ln2g = (const float*)d_in[15];
  const float* ln2b = (const float*)d_in[16];
  float* out = (float*)d_out;

  char* wsb = (char*)d_ws;
  float*  x1    = (float*)wsb;
  ushort* ffnb  = (ushort*)(wsb + 50331648);
  ushort* hb    = (ushort*)(wsb + 50331648);
  ushort* qkvb  = (ushort*)(wsb + 75497472);
  ushort* aout  = (ushort*)(wsb + 150994944);
  ushort* h2b   = (ushort*)(wsb + 201326592);
  ushort* w1t   = (ushort*)(wsb + 226492416);
  ushort* w2t   = (ushort*)(wsb + 228261888);
  ushort* wqkvt = (ushort*)(wsb + 230031360);
  ushort* wot   = (ushort*)(wsb + 230916096);
  float*  bqkv  = (float*)(wsb + 231211008);

  conv_qkvw_tiled<<<dim3(12, 2, 21), 256, 0, stream>>>(wq, wk, wv, wqkvt);
  fill_misc      <<<27, 256, 0, stream>>>(bq, bk, bv, wqkvt, bqkv);
  convT_tiled    <<<dim3(12, 12), 256, 0, stream>>>(wo, wot, EMBED, EMBED, 378, EMBED);
  convT_tiled    <<<dim3(12, 72), 256, 0, stream>>>(w1, w1t, EMBED, FFND, EMBED, FFND);
  convT_tiled    <<<dim3(72, 12), 256, 0, stream>>>(w2, w2t, FFND, EMBED, FFND, EMBED);
  pad_aout_kernel<<<(NTOK * 6 + 255) / 256, 256, 0, stream>>>(aout);

  ln_bf16_kernel<<<NTOK / 4, 256, 0, stream>>>(x, ln1g, ln1b, hb);
  mfma_gemm<EMBED / 64, EMBED * 2, EMBED * 2, 0>
      <<<dim3(NTOK / 128, QKVN / 128), 256, 0, stream>>>(
      (const char*)hb, (const char*)wqkvt, bqkv, nullptr, (char*)qkvb, QKVN);
  attn_mfma_kernel<<<BATCH * HEADS * (SEQ / 64), 256, 0, stream>>>(qkvb, aout);
  mfma_gemm<EMBED / 64, EMBED * 2, EMBED * 2, 2>
      <<<dim3(NTOK / 128, EMBED / 128), 256, 0, stream>>>(
      (const char*)aout, (const char*)wot, bo, x, (char*)x1, EMBED);
  ln_bf16_kernel<<<NTOK / 4, 256, 0, stream>>>(x1, ln2g, ln2b, h2b);
  mfma_gemm<EMBED / 64, EMBED * 2, EMBED * 2, 1>
      <<<dim3(NTOK / 128, FFND / 128), 256, 0, stream>>>(
      (const char*)h2b, (const char*)w1t, b1, nullptr, (char*)ffnb, FFND);
  mfma_gemm<FFND / 64, FFND * 2, FFND * 2, 2>
      <<<dim3(NTOK / 128, EMBED / 128), 256, 0, stream>>>(
      (const char*)ffnb, (const char*)w2t, b2, x1, (char*)out, EMBED);
}

// Round 10
// 385.764 us; speedup vs baseline: 1.2985x; 1.1578x over previous
//
#include <hip/hip_runtime.h>
#include <hip/hip_bf16.h>
#include <cmath>

#define BATCH 64
#define SEQ   512
#define EMBED 384
#define HEADS 7
#define HSZ   54
#define FFND  2304
#define NTOK  (BATCH*SEQ)
#define QKVN  1152   // 3*378 padded to 9*128
#define EPS   1e-5f
#define SCALE 0.13608276348795434f  // 54^-0.5

typedef __attribute__((ext_vector_type(8))) short s16x8;
typedef __attribute__((ext_vector_type(4))) float f32x4;

__device__ __forceinline__ ushort f2bf(float f) {
  __hip_bfloat16 h = __float2bfloat16(f);
  return *reinterpret_cast<ushort*>(&h);
}

__device__ __forceinline__ void gload16(const void* g, void* l) {
  __builtin_amdgcn_global_load_lds((const __attribute__((address_space(1))) void*)g,
                                   (__attribute__((address_space(3))) void*)l, 16, 0, 0);
}

// ---------------- LayerNorm -> bf16 out, one wave per row ----------------
__global__ __launch_bounds__(256) void ln_bf16_kernel(const float* __restrict__ x,
    const float* __restrict__ g, const float* __restrict__ b, ushort* __restrict__ out) {
  int wave = threadIdx.x >> 6, lane = threadIdx.x & 63;
  int row = (blockIdx.x << 2) + wave;
  const float* xr = x + (size_t)row * EMBED;
  float v[6]; float s = 0.f;
#pragma unroll
  for (int i = 0; i < 6; ++i) { v[i] = xr[lane + (i << 6)]; s += v[i]; }
#pragma unroll
  for (int off = 32; off; off >>= 1) s += __shfl_xor(s, off);
  float mu = s * (1.f / EMBED);
  float var = 0.f;
#pragma unroll
  for (int i = 0; i < 6; ++i) { float d = v[i] - mu; var += d * d; }
#pragma unroll
  for (int off = 32; off; off >>= 1) var += __shfl_xor(var, off);
  float rstd = rsqrtf(var * (1.f / EMBED) + EPS);
  ushort* orow = out + (size_t)row * EMBED;
#pragma unroll
  for (int i = 0; i < 6; ++i) {
    int c = lane + (i << 6);
    orow[c] = f2bf((v[i] - mu) * rstd * g[c] + b[c]);
  }
}

// ---------------- tiled transpose+convert: out[n][k] = bf16(in[k][n]), zero-padded ----------------
__global__ __launch_bounds__(256) void convT_tiled(const float* __restrict__ in,
    ushort* __restrict__ out, int K, int N, int srcK, int srcN) {
  __shared__ float t[32][33];
  int k0 = blockIdx.x << 5, n0 = blockIdx.y << 5;
  int tx = threadIdx.x & 31, ty = threadIdx.x >> 5;
#pragma unroll
  for (int i = 0; i < 4; ++i) {
    int r = ty + i * 8;
    int k = k0 + r, n = n0 + tx;
    t[r][tx] = (k < srcK && n < srcN) ? in[(size_t)k * srcN + n] : 0.f;
  }
  __syncthreads();
#pragma unroll
  for (int i = 0; i < 4; ++i) {
    int r = ty + i * 8;
    int n = n0 + r, k = k0 + tx;
    if (n < N && k < K) out[(size_t)n * K + k] = f2bf(t[tx][r]);
  }
}

// ---------------- QKV weight pack: wqkvt[n][k], n = type*378 + h*54 + hs ----------------
__global__ __launch_bounds__(256) void conv_qkvw_tiled(const float* __restrict__ wq,
    const float* __restrict__ wk, const float* __restrict__ wv, ushort* __restrict__ wt) {
  __shared__ float t[32][33];
  int k0 = blockIdx.x << 5, hs0 = blockIdx.y << 5;
  int z = blockIdx.z, type = z / 7, h = z - type * 7;
  const float* W = (type == 0) ? wq : (type == 1) ? wk : wv;
  int tx = threadIdx.x & 31, ty = threadIdx.x >> 5;
#pragma unroll
  for (int i = 0; i < 4; ++i) {
    int r = ty + i * 8;
    int k = k0 + r, hs = hs0 + tx;
    t[r][tx] = (hs < HSZ) ? W[((size_t)h * EMBED + k) * HSZ + hs] : 0.f;
  }
  __syncthreads();
#pragma unroll
  for (int i = 0; i < 4; ++i) {
    int r = ty + i * 8;
    int hs = hs0 + r, k = k0 + tx;
    if (hs < HSZ) wt[(size_t)(type * 378 + h * HSZ + hs) * EMBED + k0 + tx] = f2bf(t[tx][r]);
  }
}

// ---------------- misc fills ----------------
__global__ __launch_bounds__(256) void fill_misc(const float* __restrict__ bq,
    const float* __restrict__ bk, const float* __restrict__ bv,
    ushort* __restrict__ wt, float* __restrict__ bqkv) {
  int idx = blockIdx.x * 256 + threadIdx.x;
  if (idx < 18 * EMBED) wt[1134 * EMBED + idx] = 0;
  if (idx < QKVN) {
    float bval = 0.f;
    if (idx < 1134) {
      int type = idx / 378, rem = idx - type * 378;
      int h = rem / HSZ, hs = rem - h * HSZ;
      const float* B = (type == 0) ? bq : (type == 1) ? bk : bv;
      bval = B[h * HSZ + hs];
    }
    bqkv[idx] = bval;
  }
}

__global__ __launch_bounds__(256) void pad_aout_kernel(ushort* __restrict__ aout) {
  int idx = blockIdx.x * 256 + threadIdx.x;
  if (idx >= NTOK * 6) return;
  int row = idx / 6, c = idx - row * 6;
  aout[(size_t)row * EMBED + 378 + c] = 0;
}

// ---------------- MFMA flash attention (round-9 structure, unchanged) ----------------
__global__ __launch_bounds__(256) void attn_mfma_kernel(const ushort* __restrict__ qkv,
    ushort* __restrict__ o) {
  __shared__ ushort Ks[2][4096];
  __shared__ ushort Vt[2][4096];
  int tid = threadIdx.x;
  int id = blockIdx.x;
  int xcd = id & 7;
  int sseq = id >> 3;
  int bh = xcd + 8 * (sseq >> 3);
  int qt = (SEQ / 64 - 1) - (sseq & 7);
  int b = bh / HEADS, h = bh - b * HEADS;
  int qr0 = qt << 6;
  int w = tid >> 6, l = tid & 63;
  int lr = l & 15, lg = l >> 4;
  const ushort* base = qkv + (size_t)b * SEQ * QKVN + h * HSZ;
  const size_t TSTR = (size_t)64 * QKVN * 2;

  int grow = w * 8 + (l >> 3);
  int gc = (l & 7) ^ (l >> 3);
  const char* kg0 = (const char*)(base + 378 + (size_t)grow * QKVN + gc * 8);
  const char* kg1 = (const char*)(base + 378 + (size_t)(grow + 32) * QKVN + gc * 8);
  const char* qg0 = (const char*)(base + (size_t)(qr0 + grow) * QKVN + gc * 8);
  const char* qg1 = (const char*)(base + (size_t)(qr0 + grow + 32) * QKVN + gc * 8);
  int vdst[7]; const char* vsrc[7]; bool vpar[7];
#pragma unroll
  for (int i = 0; i < 7; ++i) {
    int e = tid + i * 256;
    int ev = e >> 1, par = e & 1;
    int p = ev / 28, cv = ev - p * 28;
    if (cv < 27) {
      int k0 = 2 * p;
      int s0 = ((k0 >> 5) << 5) | (((k0 >> 2) & 3) << 3) | (((k0 >> 4) & 1) << 2) | (k0 & 3);
      int d = 2 * cv + par;
      vdst[i] = d * 64 + (s0 ^ ((d & 7) << 3));
      vsrc[i] = (const char*)(base + 756 + (size_t)(2 * p + par) * QKVN + 2 * cv);
      vpar[i] = (par != 0);
    } else { vdst[i] = -1; vsrc[i] = (const char*)base; vpar[i] = false; }
  }

  gload16(qg0, (char*)&Ks[1][0] + w * 1024);
  gload16(qg1, (char*)&Ks[1][0] + 4096 + w * 1024);
  gload16(kg0, (char*)&Ks[0][0] + w * 1024);
  gload16(kg1, (char*)&Ks[0][0] + 4096 + w * 1024);
  uint uv[7];
#pragma unroll
  for (int i = 0; i < 7; ++i)
    uv[i] = (vdst[i] >= 0) ? *reinterpret_cast<const uint*>(vsrc[i]) : 0u;
  __syncthreads();
  for (int e = tid; e < 320; e += 256) {
    int r = e / 5, which = e - r * 5;
    int idx = (which == 0) ? (r * 64 + ((6 ^ (r & 7)) << 3) + 6)
                           : (r * 64 + ((7 ^ (r & 7)) << 3) + 2 * (which - 1));
    *reinterpret_cast<uint*>(&Ks[1][idx]) = 0;
  }
#pragma unroll
  for (int i = 0; i < 7; ++i) {
    uint u = uv[i]; uint uo = __shfl_xor(u, 1);
    if (vdst[i] >= 0) {
      uint wv2 = vpar[i] ? ((uo >> 16) | (u & 0xffff0000u)) : ((u & 0xffffu) | (uo << 16));
      *reinterpret_cast<uint*>(&Vt[0][vdst[i]]) = wv2;
    }
  }
  __syncthreads();
  int qrow = w * 16 + lr;
  s16x8 qf[2];
  qf[0] = *reinterpret_cast<const s16x8*>(&Ks[1][qrow * 64 + ((8 * lg) ^ ((qrow & 7) << 3))]);
  qf[1] = *reinterpret_cast<const s16x8*>(&Ks[1][qrow * 64 + ((32 + 8 * lg) ^ ((qrow & 7) << 3))]);
  __syncthreads();

  int qglob = qr0 + qrow;
  float mrow = -1e30f, lrow = 0.f;
  f32x4 acc[4];
#pragma unroll
  for (int d = 0; d < 4; ++d) acc[d] = (f32x4){0.f, 0.f, 0.f, 0.f};

  for (int kt = 0; kt <= qt; ++kt) {
    int cur = kt & 1, nxt = cur ^ 1;
    if (kt < qt) {
      kg0 += TSTR; kg1 += TSTR;
      gload16(kg0, (char*)&Ks[nxt][0] + w * 1024);
      gload16(kg1, (char*)&Ks[nxt][0] + 4096 + w * 1024);
#pragma unroll
      for (int i = 0; i < 7; ++i) {
        vsrc[i] += TSTR;
        if (vdst[i] >= 0) uv[i] = *reinterpret_cast<const uint*>(vsrc[i]);
      }
    }
    f32x4 sacc[4];
    __builtin_amdgcn_s_setprio(1);
#pragma unroll
    for (int kb = 0; kb < 4; ++kb) {
      sacc[kb] = (f32x4){0.f, 0.f, 0.f, 0.f};
#pragma unroll
      for (int h2 = 0; h2 < 2; ++h2) {
        int row = kb * 16 + lr;
        s16x8 kf = *reinterpret_cast<const s16x8*>(
            &Ks[cur][row * 64 + ((32 * h2 + 8 * lg) ^ ((row & 7) << 3))]);
        sacc[kb] = __builtin_amdgcn_mfma_f32_16x16x32_bf16(kf, qf[h2], sacc[kb], 0, 0, 0);
      }
    }
    __builtin_amdgcn_s_setprio(0);
    float sv[4][4];
    float mt = -1e30f;
    bool diag = (kt == qt);
#pragma unroll
    for (int kb = 0; kb < 4; ++kb)
#pragma unroll
      for (int r = 0; r < 4; ++r) {
        float s = sacc[kb][r] * SCALE;
        if (diag && (kt * 64 + kb * 16 + 4 * lg + r) > qglob) s = -1e30f;
        sv[kb][r] = s;
        mt = fmaxf(mt, s);
      }
    mt = fmaxf(mt, __shfl_xor(mt, 16));
    mt = fmaxf(mt, __shfl_xor(mt, 32));
    if (!__all(mt - mrow <= 8.f)) {
      float mnew = fmaxf(mrow, mt);
      float al = __expf(mrow - mnew);
#pragma unroll
      for (int d = 0; d < 4; ++d)
#pragma unroll
        for (int r = 0; r < 4; ++r) acc[d][r] *= al;
      lrow *= al;
      mrow = mnew;
    }
    union { short s[16]; s16x8 v[2]; } pp;
    float lsum = 0.f;
#pragma unroll
    for (int kb = 0; kb < 4; ++kb)
#pragma unroll
      for (int r = 0; r < 4; ++r) {
        float p = __expf(sv[kb][r] - mrow);
        lsum += p;
        pp.s[kb * 4 + r] = (short)f2bf(p);
      }
    lrow += lsum;
    __builtin_amdgcn_s_setprio(1);
#pragma unroll
    for (int m = 0; m < 2; ++m)
#pragma unroll
      for (int d = 0; d < 4; ++d) {
        int row = d * 16 + lr;
        s16x8 vf = *reinterpret_cast<const s16x8*>(
            &Vt[cur][row * 64 + ((32 * m + 8 * lg) ^ ((row & 7) << 3))]);
        acc[d] = __builtin_amdgcn_mfma_f32_16x16x32_bf16(vf, pp.v[m], acc[d], 0, 0, 0);
      }
    __builtin_amdgcn_s_setprio(0);
    if (kt < qt) {
#pragma unroll
      for (int i = 0; i < 7; ++i) {
        uint u = uv[i]; uint uo = __shfl_xor(u, 1);
        if (vdst[i] >= 0) {
          uint wv2 = vpar[i] ? ((uo >> 16) | (u & 0xffff0000u)) : ((u & 0xffffu) | (uo << 16));
          *reinterpret_cast<uint*>(&Vt[nxt][vdst[i]]) = wv2;
        }
      }
      __syncthreads();
    }
  }

  lrow += __shfl_xor(lrow, 16);
  lrow += __shfl_xor(lrow, 32);
  float linv = 1.f / lrow;
  __syncthreads();
  ushort* Olds = &Ks[0][0];
#pragma unroll
  for (int d = 0; d < 4; ++d)
#pragma unroll
    for (int r = 0; r < 4; ++r)
      Olds[(d * 16 + 4 * lg + r) * 64 + w * 16 + lr] = f2bf(acc[d][r] * linv);
  __syncthreads();
  for (int e = tid; e < 64 * 27; e += 256) {
    int q = e / 27, c = e - q * 27;
    uint lo = Olds[(2 * c) * 64 + q];
    uint hi = Olds[(2 * c + 1) * 64 + q];
    *reinterpret_cast<uint*>(&o[(size_t)(b * SEQ + qr0 + q) * EMBED + h * HSZ + 2 * c]) =
        lo | (hi << 16);
  }
}

// ---------------- bf16 MFMA GEMM: 128x128, BK=64, 2-phase prefetch, XCD-swizzled 1D grid ----
// grid = 256*NY blocks. Decode: xcd=id&7; t=id>>3; group=t/(4*NY); y=(t%(4*NY))>>2; xi=t&3;
// x = xcd*32 + group*4 + xi.  Same-A blocks (all NY y's of an x-chunk) run temporally
// adjacent on ONE XCD -> A-panels + whole B stay L2-resident (T1).
// MODE 0: bf16(A@B+bias)  MODE 1: bf16(fast_gelu(A@B+bias))  MODE 2: f32(A@B+bias+resid)
template<int KSTEPS, int LDA, int LDB, int MODE, int NY>
__global__ __launch_bounds__(256) void mfma_gemm(
    const char* __restrict__ Ab, const char* __restrict__ Btb,
    const float* __restrict__ bias, const float* __restrict__ resid,
    char* __restrict__ Cb, int ncols) {
  __shared__ ushort sh[32768];
  int tid = threadIdx.x;
  int id = blockIdx.x;
  int xcd = id & 7, t = id >> 3;
  int group = t / (4 * NY), rres = t - group * (4 * NY);
  int ytile = rres >> 2, xi = rres & 3;
  int tok0 = (xcd * 32 + group * 4 + xi) << 7;
  int col0 = ytile << 7;
  int wv = tid >> 6, l = tid & 63;
  int wr = wv >> 1, wc = wv & 1;
  int lr = l & 15, lg = l >> 4;

  const char* aptr[4]; const char* bptr[4];
#pragma unroll
  for (int is = 0; is < 4; ++is) {
    int i = is * 256 + tid;
    int row = i >> 3;
    int boff = (i & 7) << 4;
    int sw = boff ^ ((row & 7) << 4);
    aptr[is] = Ab + (size_t)(tok0 + row) * LDA + sw;
    bptr[is] = Btb + (size_t)(col0 + row) * LDB + sw;
  }

  int offA[2][4], offB[2][4];
#pragma unroll
  for (int m = 0; m < 4; ++m) {
    int rowa = wr * 64 + m * 16 + lr;
    int rowb = wc * 64 + m * 16 + lr;
    int sa = (rowa & 7) << 4, sb = (rowb & 7) << 4;
#pragma unroll
    for (int kk = 0; kk < 2; ++kk) {
      int kb = kk * 64 + lg * 16;
      offA[kk][m] = (rowa * 128 + (kb ^ sa)) >> 1;
      offB[kk][m] = (rowb * 128 + (kb ^ sb)) >> 1;
    }
  }

  f32x4 acc[4][4];
#pragma unroll
  for (int m = 0; m < 4; ++m)
#pragma unroll
    for (int n = 0; n < 4; ++n) acc[m][n] = (f32x4){0.f, 0.f, 0.f, 0.f};

#pragma unroll
  for (int is = 0; is < 4; ++is) {
    gload16(aptr[is], (char*)sh + is * 4096 + wv * 1024);
    gload16(bptr[is], (char*)sh + 32768 + is * 4096 + wv * 1024);
  }
  __syncthreads();

  for (int ks = 0; ks < KSTEPS; ++ks) {
    int buf = ks & 1;
    if (ks + 1 < KSTEPS) {
      int nb = buf ^ 1;
#pragma unroll
      for (int is = 0; is < 4; ++is) {
        gload16(aptr[is] + (size_t)(ks + 1) * 128, (char*)sh + nb * 16384 + is * 4096 + wv * 1024);
        gload16(bptr[is] + (size_t)(ks + 1) * 128, (char*)sh + 32768 + nb * 16384 + is * 4096 + wv * 1024);
      }
    }
    int ao = buf * 8192, bo = 16384 + buf * 8192;
    __builtin_amdgcn_s_setprio(1);
#pragma unroll
    for (int kk = 0; kk < 2; ++kk) {
      s16x8 af[4], bfr[4];
#pragma unroll
      for (int m = 0; m < 4; ++m) af[m] = *reinterpret_cast<const s16x8*>(&sh[ao + offA[kk][m]]);
#pragma unroll
      for (int n = 0; n < 4; ++n) bfr[n] = *reinterpret_cast<const s16x8*>(&sh[bo + offB[kk][n]]);
#pragma unroll
      for (int m = 0; m < 4; ++m)
#pragma unroll
        for (int n = 0; n < 4; ++n)
          acc[m][n] = __builtin_amdgcn_mfma_f32_16x16x32_bf16(af[m], bfr[n], acc[m][n], 0, 0, 0);
    }
    __builtin_amdgcn_s_setprio(0);
    if (ks + 1 < KSTEPS) __syncthreads();
  }

  float bn[4];
  int colr = col0 + wc * 64 + lr;
#pragma unroll
  for (int n = 0; n < 4; ++n) bn[n] = bias[colr + n * 16];

  if constexpr (MODE == 2) {
    int tokr = tok0 + wr * 64 + lg * 4;
    float* C = (float*)Cb;
#pragma unroll
    for (int m = 0; m < 4; ++m)
#pragma unroll
      for (int r = 0; r < 4; ++r) {
        size_t rowbase = (size_t)(tokr + m * 16 + r) * ncols;
#pragma unroll
        for (int n = 0; n < 4; ++n) {
          size_t idx = rowbase + colr + n * 16;
          C[idx] = acc[m][n][r] + bn[n] + resid[idx];
        }
      }
  } else {
    __syncthreads();
#pragma unroll
    for (int m = 0; m < 4; ++m)
#pragma unroll
      for (int r = 0; r < 4; ++r) {
        int row = wr * 64 + m * 16 + lg * 4 + r;
        int rmask = ((row >> 2) & 3) << 4;
#pragma unroll
        for (int n = 0; n < 4; ++n) {
          float xg = acc[m][n][r] + bn[n];
          if constexpr (MODE == 1) {
            float u2 = xg * (1.5957691216f + 0.0713548162f * xg * xg);
            xg = xg * __builtin_amdgcn_rcpf(1.f + __expf(-u2));
          }
          int col = wc * 64 + n * 16 + lr;
          sh[row * 128 + (col ^ rmask)] = f2bf(xg);
        }
      }
    __syncthreads();
    ushort* C = (ushort*)Cb;
    int blk = (l & 7) + 8 * (wv & 1);
    int rbase = (l >> 3) + 64 * (wv >> 1);
#pragma unroll
    for (int it = 0; it < 8; ++it) {
      int row = rbase + 8 * it;
      int pblk = blk ^ (((row >> 2) & 3) << 1);
      uint4 vvv = *reinterpret_cast<const uint4*>(&sh[row * 128 + pblk * 8]);
      *reinterpret_cast<uint4*>(&C[(size_t)(tok0 + row) * ncols + col0 + blk * 8]) = vvv;
    }
  }
}

extern "C" void kernel_launch(void* const* d_in, const int* in_sizes, int n_in,
                              void* d_out, int out_size, void* d_ws, size_t ws_size,
                              hipStream_t stream) {
  const float* x    = (const float*)d_in[0];
  const float* wq   = (const float*)d_in[1];
  const float* bq   = (const float*)d_in[2];
  const float* wk   = (const float*)d_in[3];
  const float* bk   = (const float*)d_in[4];
  const float* wv   = (const float*)d_in[5];
  const float* bv   = (const float*)d_in[6];
  const float* wo   = (const float*)d_in[7];
  const float* bo   = (const float*)d_in[8];
  const float* w1   = (const float*)d_in[9];
  const float* b1   = (const float*)d_in[10];
  const float* w2   = (const float*)d_in[11];
  const float* b2   = (const float*)d_in[12];
  const float* ln1g = (const float*)d_in[13];
  const float* ln1b = (const float*)d_in[14];
  const float* ln2g = (const float*)d_in[15];
  const float* ln2b = (const float*)d_in[16];
  float* out = (float*)d_out;

  char* wsb = (char*)d_ws;
  float*  x1    = (float*)wsb;
  ushort* ffnb  = (ushort*)(wsb + 50331648);
  ushort* hb    = (ushort*)(wsb + 50331648);
  ushort* qkvb  = (ushort*)(wsb + 75497472);
  ushort* aout  = (ushort*)(wsb + 150994944);
  ushort* h2b   = (ushort*)(wsb + 201326592);
  ushort* w1t   = (ushort*)(wsb + 226492416);
  ushort* w2t   = (ushort*)(wsb + 228261888);
  ushort* wqkvt = (ushort*)(wsb + 230031360);
  ushort* wot   = (ushort*)(wsb + 230916096);
  float*  bqkv  = (float*)(wsb + 231211008);

  conv_qkvw_tiled<<<dim3(12, 2, 21), 256, 0, stream>>>(wq, wk, wv, wqkvt);
  fill_misc      <<<27, 256, 0, stream>>>(bq, bk, bv, wqkvt, bqkv);
  convT_tiled    <<<dim3(12, 12), 256, 0, stream>>>(wo, wot, EMBED, EMBED, 378, EMBED);
  convT_tiled    <<<dim3(12, 72), 256, 0, stream>>>(w1, w1t, EMBED, FFND, EMBED, FFND);
  convT_tiled    <<<dim3(72, 12), 256, 0, stream>>>(w2, w2t, FFND, EMBED, FFND, EMBED);
  pad_aout_kernel<<<(NTOK * 6 + 255) / 256, 256, 0, stream>>>(aout);

  ln_bf16_kernel<<<NTOK / 4, 256, 0, stream>>>(x, ln1g, ln1b, hb);
  mfma_gemm<EMBED / 64, EMBED * 2, EMBED * 2, 0, QKVN / 128>
      <<<256 * (QKVN / 128), 256, 0, stream>>>(
      (const char*)hb, (const char*)wqkvt, bqkv, nullptr, (char*)qkvb, QKVN);
  attn_mfma_kernel<<<BATCH * HEADS * (SEQ / 64), 256, 0, stream>>>(qkvb, aout);
  mfma_gemm<EMBED / 64, EMBED * 2, EMBED * 2, 2, EMBED / 128>
      <<<256 * (EMBED / 128), 256, 0, stream>>>(
      (const char*)aout, (const char*)wot, bo, x, (char*)x1, EMBED);
  ln_bf16_kernel<<<NTOK / 4, 256, 0, stream>>>(x1, ln2g, ln2b, h2b);
  mfma_gemm<EMBED / 64, EMBED * 2, EMBED * 2, 1, FFND / 128>
      <<<256 * (FFND / 128), 256, 0, stream>>>(
      (const char*)h2b, (const char*)w1t, b1, nullptr, (char*)ffnb, FFND);
  mfma_gemm<FFND / 64, FFND * 2, FFND * 2, 2, EMBED / 128>
      <<<256 * (EMBED / 128), 256, 0, stream>>>(
      (const char*)ffnb, (const char*)w2t, b2, x1, (char*)out, EMBED);
}

// Round 11
// 382.956 us; speedup vs baseline: 1.3080x; 1.0073x over previous
//
#include <hip/hip_runtime.h>
#include <hip/hip_bf16.h>
#include <cmath>

#define BATCH 64
#define SEQ   512
#define EMBED 384
#define HEADS 7
#define HSZ   54
#define FFND  2304
#define NTOK  (BATCH*SEQ)
#define QKVN  1152   // 3*378 padded to 9*128
#define EPS   1e-5f
#define SCALE 0.13608276348795434f  // 54^-0.5

typedef __attribute__((ext_vector_type(8))) short s16x8;
typedef __attribute__((ext_vector_type(4))) float f32x4;

__device__ __forceinline__ ushort f2bf(float f) {
  __hip_bfloat16 h = __float2bfloat16(f);
  return *reinterpret_cast<ushort*>(&h);
}

__device__ __forceinline__ void gload16(const void* g, void* l) {
  __builtin_amdgcn_global_load_lds((const __attribute__((address_space(1))) void*)g,
                                   (__attribute__((address_space(3))) void*)l, 16, 0, 0);
}

// ---------------- LayerNorm -> bf16 out, one wave per row ----------------
__global__ __launch_bounds__(256) void ln_bf16_kernel(const float* __restrict__ x,
    const float* __restrict__ g, const float* __restrict__ b, ushort* __restrict__ out) {
  int wave = threadIdx.x >> 6, lane = threadIdx.x & 63;
  int row = (blockIdx.x << 2) + wave;
  const float* xr = x + (size_t)row * EMBED;
  float v[6]; float s = 0.f;
#pragma unroll
  for (int i = 0; i < 6; ++i) { v[i] = xr[lane + (i << 6)]; s += v[i]; }
#pragma unroll
  for (int off = 32; off; off >>= 1) s += __shfl_xor(s, off);
  float mu = s * (1.f / EMBED);
  float var = 0.f;
#pragma unroll
  for (int i = 0; i < 6; ++i) { float d = v[i] - mu; var += d * d; }
#pragma unroll
  for (int off = 32; off; off >>= 1) var += __shfl_xor(var, off);
  float rstd = rsqrtf(var * (1.f / EMBED) + EPS);
  ushort* orow = out + (size_t)row * EMBED;
#pragma unroll
  for (int i = 0; i < 6; ++i) {
    int c = lane + (i << 6);
    orow[c] = f2bf((v[i] - mu) * rstd * g[c] + b[c]);
  }
}

// ---------------- tiled transpose+convert: out[n][k] = bf16(in[k][n]), zero-padded ----------------
__global__ __launch_bounds__(256) void convT_tiled(const float* __restrict__ in,
    ushort* __restrict__ out, int K, int N, int srcK, int srcN) {
  __shared__ float t[32][33];
  int k0 = blockIdx.x << 5, n0 = blockIdx.y << 5;
  int tx = threadIdx.x & 31, ty = threadIdx.x >> 5;
#pragma unroll
  for (int i = 0; i < 4; ++i) {
    int r = ty + i * 8;
    int k = k0 + r, n = n0 + tx;
    t[r][tx] = (k < srcK && n < srcN) ? in[(size_t)k * srcN + n] : 0.f;
  }
  __syncthreads();
#pragma unroll
  for (int i = 0; i < 4; ++i) {
    int r = ty + i * 8;
    int n = n0 + r, k = k0 + tx;
    if (n < N && k < K) out[(size_t)n * K + k] = f2bf(t[tx][r]);
  }
}

// ---------------- QKV weight pack: wqkvt[n][k], n = type*378 + h*54 + hs ----------------
__global__ __launch_bounds__(256) void conv_qkvw_tiled(const float* __restrict__ wq,
    const float* __restrict__ wk, const float* __restrict__ wv, ushort* __restrict__ wt) {
  __shared__ float t[32][33];
  int k0 = blockIdx.x << 5, hs0 = blockIdx.y << 5;
  int z = blockIdx.z, type = z / 7, h = z - type * 7;
  const float* W = (type == 0) ? wq : (type == 1) ? wk : wv;
  int tx = threadIdx.x & 31, ty = threadIdx.x >> 5;
#pragma unroll
  for (int i = 0; i < 4; ++i) {
    int r = ty + i * 8;
    int k = k0 + r, hs = hs0 + tx;
    t[r][tx] = (hs < HSZ) ? W[((size_t)h * EMBED + k) * HSZ + hs] : 0.f;
  }
  __syncthreads();
#pragma unroll
  for (int i = 0; i < 4; ++i) {
    int r = ty + i * 8;
    int hs = hs0 + r, k = k0 + tx;
    if (hs < HSZ) wt[(size_t)(type * 378 + h * HSZ + hs) * EMBED + k0 + tx] = f2bf(t[tx][r]);
  }
}

// ---------------- misc fills ----------------
__global__ __launch_bounds__(256) void fill_misc(const float* __restrict__ bq,
    const float* __restrict__ bk, const float* __restrict__ bv,
    ushort* __restrict__ wt, float* __restrict__ bqkv) {
  int idx = blockIdx.x * 256 + threadIdx.x;
  if (idx < 18 * EMBED) wt[1134 * EMBED + idx] = 0;
  if (idx < QKVN) {
    float bval = 0.f;
    if (idx < 1134) {
      int type = idx / 378, rem = idx - type * 378;
      int h = rem / HSZ, hs = rem - h * HSZ;
      const float* B = (type == 0) ? bq : (type == 1) ? bk : bv;
      bval = B[h * HSZ + hs];
    }
    bqkv[idx] = bval;
  }
}

__global__ __launch_bounds__(256) void pad_aout_kernel(ushort* __restrict__ aout) {
  int idx = blockIdx.x * 256 + threadIdx.x;
  if (idx >= NTOK * 6) return;
  int row = idx / 6, c = idx - row * 6;
  aout[(size_t)row * EMBED + 378 + c] = 0;
}

// ---------------- MFMA flash attention: QBLK=128, 8 waves, causal skip ----------------
// grid 1792: xcd=id&7, sseq=id>>3; bh=xcd+8*(sseq>>2); qb=3-(sseq&3) (heavy first, same-bh
// adjacent on one XCD). Wave w owns q-rows qb*128 + w*16 + lr.
// Q staged once into Qsh[8192] (gload, swizzled; pads zeroed); reused as O-transpose buffer.
// K tiles: global_load_lds pre-swizzled (pads garbage, safe: Q pads zero). V: reg-staged
// transpose. S^T=mfma(K,Q); P lane-local; O^T=mfma(V^T,P). 1 barrier/tile.
__global__ __launch_bounds__(512) void attn_mfma_kernel(const ushort* __restrict__ qkv,
    ushort* __restrict__ o) {
  __shared__ ushort Qsh[8192];     // 128 rows x 64, swizzled; later: Olds [64 d][128 q]
  __shared__ ushort Ks[2][4096];
  __shared__ ushort Vt[2][4096];
  int tid = threadIdx.x;
  int id = blockIdx.x;
  int xcd = id & 7;
  int sseq = id >> 3;
  int bh = xcd + 8 * (sseq >> 2);
  int qb = 3 - (sseq & 3);
  int b = bh / HEADS, h = bh - b * HEADS;
  int qr0 = qb << 7;
  int ntile = 2 * qb + 2;
  int w = tid >> 6, l = tid & 63;
  int lr = l & 15, lg = l >> 4;
  const ushort* base = qkv + (size_t)b * SEQ * QKVN + h * HSZ;
  const size_t TSTR = (size_t)64 * QKVN * 2;   // bytes per 64-key tile step

  // staging geometry (once): gload lane -> row w*8+(l>>3), logical chunk (l&7)^(l>>3)
  int grow = w * 8 + (l >> 3);
  int gc = (l & 7) ^ (l >> 3);
  const char* kg  = (const char*)(base + 378 + (size_t)grow * QKVN + gc * 8);
  const char* qg0 = (const char*)(base + (size_t)(qr0 + grow) * QKVN + gc * 8);
  const char* qg1 = (const char*)(base + (size_t)(qr0 + 64 + grow) * QKVN + gc * 8);
  // V path: 4 elements per thread (512 threads x 4 >= 1728 uints)
  int vdst[4]; const char* vsrc[4]; bool vpar[4];
#pragma unroll
  for (int i = 0; i < 4; ++i) {
    int e = tid + i * 512;
    int ev = e >> 1, par = e & 1;
    int p = ev / 28, cv = ev - p * 28;
    if (cv < 27 && p < 32) {
      int k0 = 2 * p;
      int s0 = ((k0 >> 5) << 5) | (((k0 >> 2) & 3) << 3) | (((k0 >> 4) & 1) << 2) | (k0 & 3);
      int d = 2 * cv + par;
      vdst[i] = d * 64 + (s0 ^ ((d & 7) << 3));
      vsrc[i] = (const char*)(base + 756 + (size_t)(2 * p + par) * QKVN + 2 * cv);
      vpar[i] = (par != 0);
    } else { vdst[i] = -1; vsrc[i] = (const char*)base; vpar[i] = false; }
  }

  // prologue: Q (128 rows) -> Qsh, K0 -> Ks[0], V0 -> regs
  gload16(qg0, (char*)Qsh + w * 1024);
  gload16(qg1, (char*)Qsh + 8192 + w * 1024);
  gload16(kg, (char*)&Ks[0][0] + w * 1024);
  uint uv[4];
#pragma unroll
  for (int i = 0; i < 4; ++i)
    uv[i] = (vdst[i] >= 0) ? *reinterpret_cast<const uint*>(vsrc[i]) : 0u;
  __syncthreads();   // gloads + V loads complete
  // zero Q pad cols 54..63 (5 uint slots per row, swizzle-aware), commit V0
  for (int e = tid; e < 640; e += 512) {
    int r = e / 5, which = e - r * 5;
    int idx = (which == 0) ? (r * 64 + ((6 ^ (r & 7)) << 3) + 6)
                           : (r * 64 + ((7 ^ (r & 7)) << 3) + 2 * (which - 1));
    *reinterpret_cast<uint*>(&Qsh[idx]) = 0;
  }
#pragma unroll
  for (int i = 0; i < 4; ++i) {
    uint u = uv[i]; uint uo = __shfl_xor(u, 1);
    if (vdst[i] >= 0) {
      uint wv2 = vpar[i] ? ((uo >> 16) | (u & 0xffff0000u)) : ((u & 0xffffu) | (uo << 16));
      *reinterpret_cast<uint*>(&Vt[0][vdst[i]]) = wv2;
    }
  }
  __syncthreads();
  int qrow = w * 16 + lr;
  s16x8 qf[2];
  qf[0] = *reinterpret_cast<const s16x8*>(&Qsh[qrow * 64 + ((8 * lg) ^ ((qrow & 7) << 3))]);
  qf[1] = *reinterpret_cast<const s16x8*>(&Qsh[qrow * 64 + ((32 + 8 * lg) ^ ((qrow & 7) << 3))]);
  // Qsh untouched until epilogue -> no extra barrier

  int qglob = qr0 + qrow;
  float mrow = -1e30f, lrow = 0.f;
  f32x4 acc[4];
#pragma unroll
  for (int d = 0; d < 4; ++d) acc[d] = (f32x4){0.f, 0.f, 0.f, 0.f};

  for (int kt = 0; kt < ntile; ++kt) {
    int cur = kt & 1, nxt = cur ^ 1;
    if (kt + 1 < ntile) {   // prefetch next tile
      kg += TSTR;
      gload16(kg, (char*)&Ks[nxt][0] + w * 1024);
#pragma unroll
      for (int i = 0; i < 4; ++i) {
        vsrc[i] += TSTR;
        if (vdst[i] >= 0) uv[i] = *reinterpret_cast<const uint*>(vsrc[i]);
      }
    }
    // causal skip: wave fully masked for this tile? (still does staging + barrier)
    bool active = (kt * 64) <= (qr0 + w * 16 + 15);
    if (active) {
      bool diag = (kt * 64 + 63) > (qr0 + w * 16);
      f32x4 sacc[4];
      __builtin_amdgcn_s_setprio(1);
#pragma unroll
      for (int kb = 0; kb < 4; ++kb) {
        sacc[kb] = (f32x4){0.f, 0.f, 0.f, 0.f};
#pragma unroll
        for (int h2 = 0; h2 < 2; ++h2) {
          int row = kb * 16 + lr;
          s16x8 kf = *reinterpret_cast<const s16x8*>(
              &Ks[cur][row * 64 + ((32 * h2 + 8 * lg) ^ ((row & 7) << 3))]);
          sacc[kb] = __builtin_amdgcn_mfma_f32_16x16x32_bf16(kf, qf[h2], sacc[kb], 0, 0, 0);
        }
      }
      __builtin_amdgcn_s_setprio(0);
      float sv[4][4];
      float mt = -1e30f;
#pragma unroll
      for (int kb = 0; kb < 4; ++kb)
#pragma unroll
        for (int r = 0; r < 4; ++r) {
          float s = sacc[kb][r] * SCALE;
          if (diag && (kt * 64 + kb * 16 + 4 * lg + r) > qglob) s = -1e30f;
          sv[kb][r] = s;
          mt = fmaxf(mt, s);
        }
      mt = fmaxf(mt, __shfl_xor(mt, 16));
      mt = fmaxf(mt, __shfl_xor(mt, 32));
      if (!__all(mt - mrow <= 8.f)) {   // defer-max
        float mnew = fmaxf(mrow, mt);
        float al = __expf(mrow - mnew);
#pragma unroll
        for (int d = 0; d < 4; ++d)
#pragma unroll
          for (int r = 0; r < 4; ++r) acc[d][r] *= al;
        lrow *= al;
        mrow = mnew;
      }
      union { short s[16]; s16x8 v[2]; } pp;
      float lsum = 0.f;
#pragma unroll
      for (int kb = 0; kb < 4; ++kb)
#pragma unroll
        for (int r = 0; r < 4; ++r) {
          float p = __expf(sv[kb][r] - mrow);
          lsum += p;
          pp.s[kb * 4 + r] = (short)f2bf(p);
        }
      lrow += lsum;
      __builtin_amdgcn_s_setprio(1);
#pragma unroll
      for (int m = 0; m < 2; ++m)
#pragma unroll
        for (int d = 0; d < 4; ++d) {
          int row = d * 16 + lr;
          s16x8 vf = *reinterpret_cast<const s16x8*>(
              &Vt[cur][row * 64 + ((32 * m + 8 * lg) ^ ((row & 7) << 3))]);
          acc[d] = __builtin_amdgcn_mfma_f32_16x16x32_bf16(vf, pp.v[m], acc[d], 0, 0, 0);
        }
      __builtin_amdgcn_s_setprio(0);
    }
    if (kt + 1 < ntile) {
      // commit V(t+1) regs -> Vt[nxt] (safe: all waves passed previous barrier)
#pragma unroll
      for (int i = 0; i < 4; ++i) {
        uint u = uv[i]; uint uo = __shfl_xor(u, 1);
        if (vdst[i] >= 0) {
          uint wv2 = vpar[i] ? ((uo >> 16) | (u & 0xffff0000u)) : ((u & 0xffffu) | (uo << 16));
          *reinterpret_cast<uint*>(&Vt[nxt][vdst[i]]) = wv2;
        }
      }
      __syncthreads();  // drains vmcnt (K gload) + lgkm (V commit)
    }
  }

  // row sum over the 4 lanes sharing q-row lr
  lrow += __shfl_xor(lrow, 16);
  lrow += __shfl_xor(lrow, 32);
  float linv = 1.f / lrow;
  ushort* Olds = Qsh;   // [64 d][128 q]
#pragma unroll
  for (int d = 0; d < 4; ++d)
#pragma unroll
    for (int r = 0; r < 4; ++r)
      Olds[(d * 16 + 4 * lg + r) * 128 + w * 16 + lr] = f2bf(acc[d][r] * linv);
  __syncthreads();
  for (int e = tid; e < 128 * 27; e += 512) {
    int q = e / 27, c = e - q * 27;
    uint lo = Olds[(2 * c) * 128 + q];
    uint hi = Olds[(2 * c + 1) * 128 + q];
    *reinterpret_cast<uint*>(&o[(size_t)(b * SEQ + qr0 + q) * EMBED + h * HSZ + 2 * c]) =
        lo | (hi << 16);
  }
}

// ---------------- bf16 MFMA GEMM: 128x128, BK=64, 2-phase prefetch, XCD-swizzled 1D grid ----
// grid = 256*NY blocks. Decode: xcd=id&7; t=id>>3; group=t/(4*NY); y=(t%(4*NY))>>2; xi=t&3;
// x = xcd*32 + group*4 + xi.
// MODE 0: bf16(A@B+bias)  MODE 1: bf16(fast_gelu(A@B+bias))  MODE 2: f32(A@B+bias+resid)
template<int KSTEPS, int LDA, int LDB, int MODE, int NY>
__global__ __launch_bounds__(256) void mfma_gemm(
    const char* __restrict__ Ab, const char* __restrict__ Btb,
    const float* __restrict__ bias, const float* __restrict__ resid,
    char* __restrict__ Cb, int ncols) {
  __shared__ ushort sh[32768];
  int tid = threadIdx.x;
  int id = blockIdx.x;
  int xcd = id & 7, t = id >> 3;
  int group = t / (4 * NY), rres = t - group * (4 * NY);
  int ytile = rres >> 2, xi = rres & 3;
  int tok0 = (xcd * 32 + group * 4 + xi) << 7;
  int col0 = ytile << 7;
  int wv = tid >> 6, l = tid & 63;
  int wr = wv >> 1, wc = wv & 1;
  int lr = l & 15, lg = l >> 4;

  const char* aptr[4]; const char* bptr[4];
#pragma unroll
  for (int is = 0; is < 4; ++is) {
    int i = is * 256 + tid;
    int row = i >> 3;
    int boff = (i & 7) << 4;
    int sw = boff ^ ((row & 7) << 4);
    aptr[is] = Ab + (size_t)(tok0 + row) * LDA + sw;
    bptr[is] = Btb + (size_t)(col0 + row) * LDB + sw;
  }

  int offA[2][4], offB[2][4];
#pragma unroll
  for (int m = 0; m < 4; ++m) {
    int rowa = wr * 64 + m * 16 + lr;
    int rowb = wc * 64 + m * 16 + lr;
    int sa = (rowa & 7) << 4, sb = (rowb & 7) << 4;
#pragma unroll
    for (int kk = 0; kk < 2; ++kk) {
      int kb = kk * 64 + lg * 16;
      offA[kk][m] = (rowa * 128 + (kb ^ sa)) >> 1;
      offB[kk][m] = (rowb * 128 + (kb ^ sb)) >> 1;
    }
  }

  f32x4 acc[4][4];
#pragma unroll
  for (int m = 0; m < 4; ++m)
#pragma unroll
    for (int n = 0; n < 4; ++n) acc[m][n] = (f32x4){0.f, 0.f, 0.f, 0.f};

#pragma unroll
  for (int is = 0; is < 4; ++is) {
    gload16(aptr[is], (char*)sh + is * 4096 + wv * 1024);
    gload16(bptr[is], (char*)sh + 32768 + is * 4096 + wv * 1024);
  }
  __syncthreads();

  for (int ks = 0; ks < KSTEPS; ++ks) {
    int buf = ks & 1;
    if (ks + 1 < KSTEPS) {
      int nb = buf ^ 1;
#pragma unroll
      for (int is = 0; is < 4; ++is) {
        gload16(aptr[is] + (size_t)(ks + 1) * 128, (char*)sh + nb * 16384 + is * 4096 + wv * 1024);
        gload16(bptr[is] + (size_t)(ks + 1) * 128, (char*)sh + 32768 + nb * 16384 + is * 4096 + wv * 1024);
      }
    }
    int ao = buf * 8192, bo = 16384 + buf * 8192;
    __builtin_amdgcn_s_setprio(1);
#pragma unroll
    for (int kk = 0; kk < 2; ++kk) {
      s16x8 af[4], bfr[4];
#pragma unroll
      for (int m = 0; m < 4; ++m) af[m] = *reinterpret_cast<const s16x8*>(&sh[ao + offA[kk][m]]);
#pragma unroll
      for (int n = 0; n < 4; ++n) bfr[n] = *reinterpret_cast<const s16x8*>(&sh[bo + offB[kk][n]]);
#pragma unroll
      for (int m = 0; m < 4; ++m)
#pragma unroll
        for (int n = 0; n < 4; ++n)
          acc[m][n] = __builtin_amdgcn_mfma_f32_16x16x32_bf16(af[m], bfr[n], acc[m][n], 0, 0, 0);
    }
    __builtin_amdgcn_s_setprio(0);
    if (ks + 1 < KSTEPS) __syncthreads();
  }

  float bn[4];
  int colr = col0 + wc * 64 + lr;
#pragma unroll
  for (int n = 0; n < 4; ++n) bn[n] = bias[colr + n * 16];

  if constexpr (MODE == 2) {
    int tokr = tok0 + wr * 64 + lg * 4;
    float* C = (float*)Cb;
#pragma unroll
    for (int m = 0; m < 4; ++m)
#pragma unroll
      for (int r = 0; r < 4; ++r) {
        size_t rowbase = (size_t)(tokr + m * 16 + r) * ncols;
#pragma unroll
        for (int n = 0; n < 4; ++n) {
          size_t idx = rowbase + colr + n * 16;
          C[idx] = acc[m][n][r] + bn[n] + resid[idx];
        }
      }
  } else {
    __syncthreads();
#pragma unroll
    for (int m = 0; m < 4; ++m)
#pragma unroll
      for (int r = 0; r < 4; ++r) {
        int row = wr * 64 + m * 16 + lg * 4 + r;
        int rmask = ((row >> 2) & 3) << 4;
#pragma unroll
        for (int n = 0; n < 4; ++n) {
          float xg = acc[m][n][r] + bn[n];
          if constexpr (MODE == 1) {
            float u2 = xg * (1.5957691216f + 0.0713548162f * xg * xg);
            xg = xg * __builtin_amdgcn_rcpf(1.f + __expf(-u2));
          }
          int col = wc * 64 + n * 16 + lr;
          sh[row * 128 + (col ^ rmask)] = f2bf(xg);
        }
      }
    __syncthreads();
    ushort* C = (ushort*)Cb;
    int blk = (l & 7) + 8 * (wv & 1);
    int rbase = (l >> 3) + 64 * (wv >> 1);
#pragma unroll
    for (int it = 0; it < 8; ++it) {
      int row = rbase + 8 * it;
      int pblk = blk ^ (((row >> 2) & 3) << 1);
      uint4 vvv = *reinterpret_cast<const uint4*>(&sh[row * 128 + pblk * 8]);
      *reinterpret_cast<uint4*>(&C[(size_t)(tok0 + row) * ncols + col0 + blk * 8]) = vvv;
    }
  }
}

extern "C" void kernel_launch(void* const* d_in, const int* in_sizes, int n_in,
                              void* d_out, int out_size, void* d_ws, size_t ws_size,
                              hipStream_t stream) {
  const float* x    = (const float*)d_in[0];
  const float* wq   = (const float*)d_in[1];
  const float* bq   = (const float*)d_in[2];
  const float* wk   = (const float*)d_in[3];
  const float* bk   = (const float*)d_in[4];
  const float* wv   = (const float*)d_in[5];
  const float* bv   = (const float*)d_in[6];
  const float* wo   = (const float*)d_in[7];
  const float* bo   = (const float*)d_in[8];
  const float* w1   = (const float*)d_in[9];
  const float* b1   = (const float*)d_in[10];
  const float* w2   = (const float*)d_in[11];
  const float* b2   = (const float*)d_in[12];
  const float* ln1g = (const float*)d_in[13];
  const float* ln1b = (const float*)d_in[14];
  const float* ln2g = (const float*)d_in[15];
  const float* ln2b = (const float*)d_in[16];
  float* out = (float*)d_out;

  char* wsb = (char*)d_ws;
  float*  x1    = (float*)wsb;
  ushort* ffnb  = (ushort*)(wsb + 50331648);
  ushort* hb    = (ushort*)(wsb + 50331648);
  ushort* qkvb  = (ushort*)(wsb + 75497472);
  ushort* aout  = (ushort*)(wsb + 150994944);
  ushort* h2b   = (ushort*)(wsb + 201326592);
  ushort* w1t   = (ushort*)(wsb + 226492416);
  ushort* w2t   = (ushort*)(wsb + 228261888);
  ushort* wqkvt = (ushort*)(wsb + 230031360);
  ushort* wot   = (ushort*)(wsb + 230916096);
  float*  bqkv  = (float*)(wsb + 231211008);

  conv_qkvw_tiled<<<dim3(12, 2, 21), 256, 0, stream>>>(wq, wk, wv, wqkvt);
  fill_misc      <<<27, 256, 0, stream>>>(bq, bk, bv, wqkvt, bqkv);
  convT_tiled    <<<dim3(12, 12), 256, 0, stream>>>(wo, wot, EMBED, EMBED, 378, EMBED);
  convT_tiled    <<<dim3(12, 72), 256, 0, stream>>>(w1, w1t, EMBED, FFND, EMBED, FFND);
  convT_tiled    <<<dim3(72, 12), 256, 0, stream>>>(w2, w2t, FFND, EMBED, FFND, EMBED);
  pad_aout_kernel<<<(NTOK * 6 + 255) / 256, 256, 0, stream>>>(aout);

  ln_bf16_kernel<<<NTOK / 4, 256, 0, stream>>>(x, ln1g, ln1b, hb);
  mfma_gemm<EMBED / 64, EMBED * 2, EMBED * 2, 0, QKVN / 128>
      <<<256 * (QKVN / 128), 256, 0, stream>>>(
      (const char*)hb, (const char*)wqkvt, bqkv, nullptr, (char*)qkvb, QKVN);
  attn_mfma_kernel<<<BATCH * HEADS * 4, 512, 0, stream>>>(qkvb, aout);
  mfma_gemm<EMBED / 64, EMBED * 2, EMBED * 2, 2, EMBED / 128>
      <<<256 * (EMBED / 128), 256, 0, stream>>>(
      (const char*)aout, (const char*)wot, bo, x, (char*)x1, EMBED);
  ln_bf16_kernel<<<NTOK / 4, 256, 0, stream>>>(x1, ln2g, ln2b, h2b);
  mfma_gemm<EMBED / 64, EMBED * 2, EMBED * 2, 1, FFND / 128>
      <<<256 * (FFND / 128), 256, 0, stream>>>(
      (const char*)h2b, (const char*)w1t, b1, nullptr, (char*)ffnb, FFND);
  mfma_gemm<FFND / 64, FFND * 2, FFND * 2, 2, EMBED / 128>
      <<<256 * (EMBED / 128), 256, 0, stream>>>(
      (const char*)ffnb, (const char*)w2t, b2, x1, (char*)out, EMBED);
}